// Round 17
// baseline (432.334 us; speedup 1.0000x reference)
//
#include <hip/hip_runtime.h>
#include <hip/hip_bf16.h>
#include <cstdint>
#include <cstddef>

using bf16 = __hip_bfloat16;
typedef __attribute__((ext_vector_type(8))) short short8v;   // MFMA A/B frag: 8 bf16
typedef __attribute__((ext_vector_type(4))) short short4v;   // 4 bf16 (b64 load/store)
typedef __attribute__((ext_vector_type(4))) float float4v;   // MFMA C/D frag

__device__ inline float b2f(short s) {
  union { float f; uint32_t u; } z; z.u = ((uint32_t)(uint16_t)s) << 16; return z.f;
}
__device__ inline short f2b(float f) {
  bf16 h = __float2bfloat16(f);
  return *reinterpret_cast<short*>(&h);
}

typedef const __attribute__((address_space(1))) uint32_t* gas1p;
typedef __attribute__((address_space(3))) uint32_t* las3p;
__device__ inline void gload_lds16(const void* g, void* l) {
  __builtin_amdgcn_global_load_lds((gas1p)g, (las3p)l, 16, 0, 0);
}

// T1 XCD swizzle. Round-11 PMC confirmed: co-locates panel-sharing blocks on
// one XCD's L2 (gemm_pipe FETCH dropped 135 MB -> 32.8 MB compulsory).
__device__ inline void xcd_swizzle(int& bx, int& by, int& bz) {
  const int gx = gridDim.x, gy = gridDim.y;
  const int nwg = gx * gy * gridDim.z;
  const int wgid = blockIdx.x + gx * (blockIdx.y + gy * blockIdx.z);
  const int swz = (wgid & 7) * (nwg >> 3) + (wgid >> 3);
  bx = swz % gx;
  by = (swz / gx) % gy;
  bz = swz / (gx * gy);
}

// ---------------------------------------------------------------------------
// 128²-tile GEMM for QKV/FF1: BK=64 as two BK=32 halves, double-buffered LDS,
// ONE barrier/iter, XCD swizzle; bias/ReLU/bf16 epilogue. LDS 64 KB ->
// 2 blocks/CU resident.
// ---------------------------------------------------------------------------
__global__ __launch_bounds__(256) void gemm_bt128(
    const bf16* __restrict__ A, const bf16* __restrict__ Bt,
    const float* __restrict__ bias, void* __restrict__ C,
    int K, int ldc, int relu_mode, int out_f32) {
  __shared__ __align__(16) bf16 As[2][2][128 * 32];  // [buf][half][tile]
  __shared__ __align__(16) bf16 Bs[2][2][128 * 32];
  const int tid = threadIdx.x;
  const int w = tid >> 6, lane = tid & 63;
  const int quad = lane >> 4, l16 = lane & 15;
  const int wrow = (w >> 1) * 64, wcol = (w & 1) * 64;
  int bx, by, bz;
  xcd_swizzle(bx, by, bz);
  const int mbase = by * 128, nbase = bx * 128;
  const int c0 = w * 128 + lane;           // chunk ids c0 and c0+64
  const int row0 = c0 >> 2, p0 = c0 & 3;
  const int row1 = (c0 + 64) >> 2, p1 = (c0 + 64) & 3;

  const bf16* ag0 = A + (size_t)(mbase + row0) * K + p0 * 8;
  const bf16* ag1 = A + (size_t)(mbase + row1) * K + p1 * 8;
  const bf16* bg0 = Bt + (size_t)(nbase + row0) * K + p0 * 8;
  const bf16* bg1 = Bt + (size_t)(nbase + row1) * K + p1 * 8;

  // stage 64-col tile t64 into buffer bi (two BK=32 halves)
  auto stage = [&](int t64, int bi) {
    const int ko = t64 * 64;
#pragma unroll
    for (int h = 0; h < 2; h++) {
      char* da = (char*)As + (size_t)(bi * 2 + h) * 8192 + w * 2048;
      char* db = (char*)Bs + (size_t)(bi * 2 + h) * 8192 + w * 2048;
      gload_lds16(ag0 + ko + h * 32, da);
      gload_lds16(ag1 + ko + h * 32, da + 1024);
      gload_lds16(bg0 + ko + h * 32, db);
      gload_lds16(bg1 + ko + h * 32, db + 1024);
    }
  };

  float4v acc[4][4];
  for (int i = 0; i < 4; i++)
    for (int j = 0; j < 4; j++) acc[i][j] = (float4v){0.f, 0.f, 0.f, 0.f};

  const int KT2 = K >> 6;
  // prologue: tile 0 -> buf 0
  stage(0, 0);
  __syncthreads();

  for (int kt = 0; kt < KT2; kt++) {
    const int pb = kt & 1;
    if (kt + 1 < KT2) stage(kt + 1, 1 - pb);  // issued early, drained at barrier

#pragma unroll
    for (int h = 0; h < 2; h++) {
      const bf16* Ah = &As[pb][h][0];
      const bf16* Bh = &Bs[pb][h][0];
      short8v a[4], b[4];
      for (int mt = 0; mt < 4; mt++)
        a[mt] = *reinterpret_cast<const short8v*>(Ah + (wrow + mt * 16 + l16) * 32 + quad * 8);
      for (int nt = 0; nt < 4; nt++)
        b[nt] = *reinterpret_cast<const short8v*>(Bh + (wcol + nt * 16 + l16) * 32 + quad * 8);
      for (int mt = 0; mt < 4; mt++)
        for (int nt = 0; nt < 4; nt++)
          acc[mt][nt] = __builtin_amdgcn_mfma_f32_16x16x32_bf16(a[mt], b[nt], acc[mt][nt], 0, 0, 0);
    }

    __syncthreads();  // drains vmcnt (next tile valid) + lgkm (reads done)
  }

  // epilogue: D row = quad*4+reg, col = lane&15
  for (int nt = 0; nt < 4; nt++) {
    int col = nbase + wcol + nt * 16 + l16;
    float bv = bias[col];
    for (int mt = 0; mt < 4; mt++) {
      int row = mbase + wrow + mt * 16 + quad * 4;
      for (int r = 0; r < 4; r++) {
        float v = acc[mt][nt][r] + bv;
        if (relu_mode) v = fmaxf(v, 0.f);
        size_t idx = (size_t)(row + r) * ldc + col;
        if (out_f32) ((float*)C)[idx] = v;
        else         ((short*)C)[idx] = f2b(v);
      }
    }
  }
}

// ---------------------------------------------------------------------------
// Pipelined split-K GEMM for WO/FF2. v4: BK=64 per barrier as two BK=32
// halves, double-buffered, one barrier/iter, + T1 XCD swizzle. Split-K FIXED
// at 2 (round-15: split-K=4 regressed via atomic contention at the LDS-capped
// 2 blocks/CU). blockIdx.z selects a K-slice; partial sums atomicAdd into
// fp32 C (bias pre-initialized).
// ---------------------------------------------------------------------------
__global__ __launch_bounds__(256) void gemm_pipe(
    const bf16* __restrict__ A, const bf16* __restrict__ Bt,
    float* __restrict__ C, int K, int ldc, int k_len) {
  __shared__ __align__(16) bf16 As[2][2][128 * 32];  // [buf][half][tile]
  __shared__ __align__(16) bf16 Bs[2][2][128 * 32];
  const int tid = threadIdx.x;
  const int w = tid >> 6, lane = tid & 63;
  const int quad = lane >> 4, l16 = lane & 15;
  const int wrow = (w >> 1) * 64, wcol = (w & 1) * 64;
  int bx, by, bz;
  xcd_swizzle(bx, by, bz);
  const int mbase = by * 128, nbase = bx * 128;
  const int c0 = w * 128 + lane;           // chunk ids c0 and c0+64
  const int row0 = c0 >> 2, p0 = c0 & 3;
  const int row1 = (c0 + 64) >> 2, p1 = (c0 + 64) & 3;
  const int kbase = bz * k_len;

  const bf16* ag0 = A + (size_t)(mbase + row0) * K + kbase + p0 * 8;
  const bf16* ag1 = A + (size_t)(mbase + row1) * K + kbase + p1 * 8;
  const bf16* bg0 = Bt + (size_t)(nbase + row0) * K + kbase + p0 * 8;
  const bf16* bg1 = Bt + (size_t)(nbase + row1) * K + kbase + p1 * 8;

  // stage 64-col tile t64 into buffer bi (two BK=32 halves)
  auto stage = [&](int t64, int bi) {
    const int ko = t64 * 64;
#pragma unroll
    for (int h = 0; h < 2; h++) {
      char* da = (char*)As + (size_t)(bi * 2 + h) * 8192 + w * 2048;
      char* db = (char*)Bs + (size_t)(bi * 2 + h) * 8192 + w * 2048;
      gload_lds16(ag0 + ko + h * 32, da);
      gload_lds16(ag1 + ko + h * 32, da + 1024);
      gload_lds16(bg0 + ko + h * 32, db);
      gload_lds16(bg1 + ko + h * 32, db + 1024);
    }
  };

  float4v acc[4][4];
  for (int i = 0; i < 4; i++)
    for (int j = 0; j < 4; j++) acc[i][j] = (float4v){0.f, 0.f, 0.f, 0.f};

  const int KT2 = k_len >> 6;
  // prologue: tile 0 -> buf 0
  stage(0, 0);
  __syncthreads();

  for (int kt = 0; kt < KT2; kt++) {
    const int pb = kt & 1;
    if (kt + 1 < KT2) stage(kt + 1, 1 - pb);  // issued early, drained at barrier

#pragma unroll
    for (int h = 0; h < 2; h++) {
      const bf16* Ah = &As[pb][h][0];
      const bf16* Bh = &Bs[pb][h][0];
      short8v a[4], b[4];
      for (int mt = 0; mt < 4; mt++)
        a[mt] = *reinterpret_cast<const short8v*>(Ah + (wrow + mt * 16 + l16) * 32 + quad * 8);
      for (int nt = 0; nt < 4; nt++)
        b[nt] = *reinterpret_cast<const short8v*>(Bh + (wcol + nt * 16 + l16) * 32 + quad * 8);
      for (int mt = 0; mt < 4; mt++)
        for (int nt = 0; nt < 4; nt++)
          acc[mt][nt] = __builtin_amdgcn_mfma_f32_16x16x32_bf16(a[mt], b[nt], acc[mt][nt], 0, 0, 0);
    }

    __syncthreads();  // drains vmcnt (next tile valid) + lgkm (reads done)
  }

  // epilogue: partial-sum atomicAdd (C pre-initialized with bias)
  for (int nt = 0; nt < 4; nt++) {
    int col = nbase + wcol + nt * 16 + l16;
    for (int mt = 0; mt < 4; mt++) {
      int row = mbase + wrow + mt * 16 + quad * 4;
      for (int r = 0; r < 4; r++)
        atomicAdd(&C[(size_t)(row + r) * ldc + col], acc[mt][nt][r]);
    }
  }
}

// C[row, 0..N) = bias[0..N), fp32. grid = rows, block 256, N = 1024.
__global__ __launch_bounds__(256) void bias_init(
    const float* __restrict__ bias, float* __restrict__ C) {
  int c = threadIdx.x * 4;
  float4 bv = *reinterpret_cast<const float4*>(bias + c);
  *reinterpret_cast<float4*>(C + (size_t)blockIdx.x * 1024 + c) = bv;
}

// ---------------------------------------------------------------------------
// Flash attention v11: KVBLK=128 (four 32-kv subtiles per barrier) — 16
// iterations. The barrier-count lever (32->64 kv in round 11 gave ~-15 µs)
// extended one more notch; GEMMs can't take it (LDS), attn can: Ks 32 KB +
// Vt 34 KB = 66 KB -> still 2 blocks/CU. Vt pitch 136 shorts (68 dwords;
// 68%32 == 36%32 == 4, same bank-alias structure as KVBLK=64). Subtile j
// pointer offset 6144*j (32 kv rows = 2 qkv rows, exact). Swizzles unchanged
// ((krow+32j)&7 == krow&7).
// ---------------------------------------------------------------------------
__global__ __launch_bounds__(256) void attn_kernel(
    const bf16* __restrict__ qkv, const int* __restrict__ mask,
    bf16* __restrict__ ao) {
  __shared__ __align__(16) short Vt[2][64 * 136];  // [buf][d][kv0..127], pitch 136
  __shared__ __align__(16) short Ks[2][128 * 64];  // [buf][kv][d], row-XOR-swizzled

  const int tid = threadIdx.x;
  const int w = tid >> 6, lane = tid & 63;
  const int quad = lane >> 4, l16 = lane & 15;
  const int bh = blockIdx.y, b = bh >> 4;
  const int row0 = bh * 128;                 // row base in qkv [4096,3072]
  const int qbase = blockIdx.x * 128 + w * 32;  // wave's 32 q rows
  const int kvp = tid & 15, dg = tid >> 4;   // V stager: kv rows 2kvp,2kvp+1; d 4dg..+3
  const int krow = tid >> 3, kc = tid & 7;   // K stager: rows krow+32j, chunk kc

  // Q fragments (B-operand of swapped QK^T); Q is pre-scaled by log2(e)/8
  short8v aq[2][2];
  for (int h = 0; h < 2; h++)
    for (int dh = 0; dh < 2; dh++) {
      int local = (qbase + h * 16 + l16) * 64 + dh * 32 + quad * 8;
      aq[h][dh] = *reinterpret_cast<const short8v*>(
          qkv + (size_t)(row0 + (local >> 10)) * 3072 + (local & 1023));
    }

  // K stage base pointer (4 b128/thread cover the 128x64 tile, +6144*j)
  const bf16* pks0;
  {
    int local = krow * 64 + kc * 8;
    pks0 = qkv + (size_t)(row0 + (local >> 10)) * 3072 + (local & 1023) + 1024;
  }
  // V stage base pointers (2 kv rows x 4 d per thread, x4 subtiles at +6144*j)
  const bf16* pva0;
  const bf16* pvb0;
  {
    int la = (2 * kvp) * 64 + dg * 4;
    pva0 = qkv + (size_t)(row0 + (la >> 10)) * 3072 + (la & 1023) + 2048;
    int lb = (2 * kvp + 1) * 64 + dg * 4;
    pvb0 = qkv + (size_t)(row0 + (lb >> 10)) * 3072 + (lb & 1023) + 2048;
  }
  const int* pm = mask + b * 2048 + quad * 4;

  float4v o[2][4];
  for (int h = 0; h < 2; h++)
    for (int nt = 0; nt < 4; nt++) o[h][nt] = (float4v){0.f, 0.f, 0.f, 0.f};
  float4v lacc[2];
  lacc[0] = (float4v){0.f, 0.f, 0.f, 0.f};
  lacc[1] = (float4v){0.f, 0.f, 0.f, 0.f};
  short8v vone;
  for (int j = 0; j < 8; j++) vone[j] = (short)0x3F80;  // bf16 1.0 x8

  // prologue: load + stage tile 0 (128 kv rows)
  short8v kr[4];
  short4v va[4], vb[4];
  int4 mcs[8];
#pragma unroll
  for (int j = 0; j < 4; j++) {
    kr[j] = *reinterpret_cast<const short8v*>(pks0 + 6144 * j);
    va[j] = *reinterpret_cast<const short4v*>(pva0 + 6144 * j);
    vb[j] = *reinterpret_cast<const short4v*>(pvb0 + 6144 * j);
  }
#pragma unroll
  for (int q = 0; q < 8; q++) mcs[q] = *reinterpret_cast<const int4*>(pm + 16 * q);
  pks0 += 24576; pva0 += 24576; pvb0 += 24576; pm += 128;
  {
    const int sw = (kc ^ (krow & 7)) << 3;
    uint32_t* vt = reinterpret_cast<uint32_t*>(&Vt[0][0]);
#pragma unroll
    for (int j = 0; j < 4; j++) {
      *reinterpret_cast<short8v*>(&Ks[0][(krow + 32 * j) * 64 + sw]) = kr[j];
#pragma unroll
      for (int i = 0; i < 4; i++)
        vt[(dg * 4 + i) * 68 + j * 16 + kvp] =
            ((uint32_t)(uint16_t)vb[j][i] << 16) | (uint16_t)(uint16_t)va[j][i];
    }
  }
  __syncthreads();

  for (int it = 0; it < 16; it++) {
    const int pb = it & 1;
    short8v knr[4];
    short4v vna[4], vnb[4];
    int4 mns[8];
    if (it < 15) {
#pragma unroll
      for (int j = 0; j < 4; j++) {
        knr[j] = *reinterpret_cast<const short8v*>(pks0 + 6144 * j);
        vna[j] = *reinterpret_cast<const short4v*>(pva0 + 6144 * j);
        vnb[j] = *reinterpret_cast<const short4v*>(pvb0 + 6144 * j);
      }
#pragma unroll
      for (int q = 0; q < 8; q++) mns[q] = *reinterpret_cast<const int4*>(pm + 16 * q);
      pks0 += 24576; pva0 += 24576; pvb0 += 24576; pm += 128;
    }

#pragma unroll
    for (int sub = 0; sub < 4; sub++) {
      // K fragments from LDS (swizzled read: chunk (dh*4+quad) ^ (l16&7))
      short8v kc_[2][2];
      for (int s = 0; s < 2; s++)
        for (int dh = 0; dh < 2; dh++) {
          int rr = sub * 32 + s * 16 + l16;
          kc_[s][dh] = *reinterpret_cast<const short8v*>(
              &Ks[pb][rr * 64 + (((dh * 4 + quad) ^ (l16 & 7)) << 3)]);
        }

      float4v st[2][2];
      for (int s = 0; s < 2; s++)
        for (int h = 0; h < 2; h++) {
          float4v t = (float4v){0.f, 0.f, 0.f, 0.f};
          t = __builtin_amdgcn_mfma_f32_16x16x32_bf16(kc_[s][0], aq[h][0], t, 0, 0, 0);
          t = __builtin_amdgcn_mfma_f32_16x16x32_bf16(kc_[s][1], aq[h][1], t, 0, 0, 0);
          st[s][h] = t;
        }

      // softmax numerator + in-register P-fragment assembly (no LDS)
      short8v pf[2];
      for (int h = 0; h < 2; h++) {
        float ev[2][4];
        for (int s = 0; s < 2; s++) {
          int4 mv = mcs[sub * 2 + s];
          int mm[4] = {mv.x, mv.y, mv.z, mv.w};
          for (int r = 0; r < 4; r++) {
            float y = st[s][h][r];                    // already exp2-arg units
            y = (mm[r] == 0) ? -1.4427e-12f : y;      // faithful mask semantics
            ev[s][r] = __builtin_amdgcn_exp2f(y);
          }
        }
        uint32_t a0, a1, b0, b1;
        asm("v_cvt_pk_bf16_f32 %0, %1, %2" : "=v"(a0) : "v"(ev[0][0]), "v"(ev[0][1]));
        asm("v_cvt_pk_bf16_f32 %0, %1, %2" : "=v"(a1) : "v"(ev[0][2]), "v"(ev[0][3]));
        asm("v_cvt_pk_bf16_f32 %0, %1, %2" : "=v"(b0) : "v"(ev[1][0]), "v"(ev[1][1]));
        asm("v_cvt_pk_bf16_f32 %0, %1, %2" : "=v"(b1) : "v"(ev[1][2]), "v"(ev[1][3]));
        // halves: lanes<32 hold A-family (s=0), >=32 B-family (s=1)
        asm("v_permlane32_swap_b32 %0, %1" : "+v"(b0), "+v"(a0));
        asm("v_permlane16_swap_b32 %0, %1" : "+v"(b0), "+v"(a0));
        asm("v_permlane32_swap_b32 %0, %1" : "+v"(b1), "+v"(a1));
        asm("v_permlane16_swap_b32 %0, %1" : "+v"(b1), "+v"(a1));
        union { short8v s8; uint32_t u[4]; } pfu;
        pfu.u[0] = a0; pfu.u[1] = a1; pfu.u[2] = b0; pfu.u[3] = b1;
        pf[h] = pfu.s8;
      }

      for (int h = 0; h < 2; h++)
        lacc[h] = __builtin_amdgcn_mfma_f32_16x16x32_bf16(pf[h], vone, lacc[h], 0, 0, 0);
      for (int nt = 0; nt < 4; nt++) {
        short8v bv = *reinterpret_cast<const short8v*>(
            &Vt[pb][(nt * 16 + l16) * 136 + sub * 32 + quad * 8]);
        for (int h = 0; h < 2; h++)
          o[h][nt] = __builtin_amdgcn_mfma_f32_16x16x32_bf16(pf[h], bv, o[h][nt], 0, 0, 0);
      }
    }

    if (it < 15) {
      const int sw = (kc ^ (krow & 7)) << 3;
      uint32_t* vt = reinterpret_cast<uint32_t*>(&Vt[1 - pb][0]);
#pragma unroll
      for (int j = 0; j < 4; j++) {
        *reinterpret_cast<short8v*>(&Ks[1 - pb][(krow + 32 * j) * 64 + sw]) = knr[j];
#pragma unroll
        for (int i = 0; i < 4; i++)
          vt[(dg * 4 + i) * 68 + j * 16 + kvp] =
              ((uint32_t)(uint16_t)vnb[j][i] << 16) | (uint16_t)(uint16_t)vna[j][i];
      }
#pragma unroll
      for (int q = 0; q < 8; q++) mcs[q] = mns[q];
    }
    __syncthreads();
  }

  // lacc[h][r] = rowsum(P) for q row quad*4+r (all 16 cols identical)
  for (int h = 0; h < 2; h++)
    for (int r = 0; r < 4; r++) {
      float linv = 1.0f / lacc[h][r];
      int qg = qbase + h * 16 + quad * 4 + r;
      for (int nt = 0; nt < 4; nt++) {
        int d = nt * 16 + l16;
        ao[(size_t)bh * 131072 + (size_t)qg * 64 + d] = __float2bfloat16(o[h][nt][r] * linv);
      }
    }
}

// ---------------------------------------------------------------------------
// out = LN(a + xres); unbiased std (ddof=1), /(std + 1e-12). One block / row.
// ---------------------------------------------------------------------------
__global__ __launch_bounds__(256) void ln_resid(
    const void* __restrict__ a, const void* __restrict__ xres,
    const float* __restrict__ gamma, const float* __restrict__ beta,
    void* __restrict__ out, int a_f32, int x_f32, int out_f32) {
  __shared__ float red[8];
  const int row = blockIdx.x, tid = threadIdx.x;
  const int w = tid >> 6, lane = tid & 63;
  const size_t base = (size_t)row * 1024;
  float v[4]; float sum = 0.f, ss = 0.f;
  for (int i = 0; i < 4; i++) {
    int c = tid + i * 256;
    float av = a_f32 ? ((const float*)a)[base + c] : b2f(((const short*)a)[base + c]);
    float xv = x_f32 ? ((const float*)xres)[base + c] : b2f(((const short*)xres)[base + c]);
    v[i] = av + xv;
    sum += v[i]; ss += v[i] * v[i];
  }
  for (int off = 1; off < 64; off <<= 1) {
    sum += __shfl_xor(sum, off);
    ss  += __shfl_xor(ss, off);
  }
  if (lane == 0) { red[w * 2] = sum; red[w * 2 + 1] = ss; }
  __syncthreads();
  sum = red[0] + red[2] + red[4] + red[6];
  ss  = red[1] + red[3] + red[5] + red[7];
  float mean = sum * (1.0f / 1024.0f);
  float var = (ss - 1024.0f * mean * mean) * (1.0f / 1023.0f);
  var = fmaxf(var, 0.f);
  float rden = 1.0f / (sqrtf(var) + 1e-12f);
  for (int i = 0; i < 4; i++) {
    int c = tid + i * 256;
    float y = gamma[c] * ((v[i] - mean) * rden) + beta[c];
    if (out_f32) ((float*)out)[base + c] = y;
    else         ((short*)out)[base + c] = f2b(y);
  }
}

// out(bf16)[c*R + r] = in(f32)[r*C + c] * scale; R,C % 32 == 0.
__global__ __launch_bounds__(256) void transpose_k(
    const float* __restrict__ in, bf16* __restrict__ out, int R, int C,
    float scale) {
  __shared__ short t[32][33];
  const int tx = threadIdx.x, ty = threadIdx.y;
  const int cb = blockIdx.x * 32, rb = blockIdx.y * 32;
  for (int j = 0; j < 4; j++)
    t[ty + j * 8][tx] = f2b(in[(size_t)(rb + ty + j * 8) * C + cb + tx] * scale);
  __syncthreads();
  for (int j = 0; j < 4; j++)
    ((short*)out)[(size_t)(cb + ty + j * 8) * R + rb + tx] = t[tx][ty + j * 8];
}

// q-bias scaled by log2(e)/8 to match the pre-scaled Q projection.
__global__ __launch_bounds__(256) void concat3(
    const float* __restrict__ a, const float* __restrict__ b,
    const float* __restrict__ c, float* __restrict__ out) {
  int i = blockIdx.x * 256 + threadIdx.x;  // grid 12 -> 3072
  float v;
  if (i < 1024)       v = a[i] * 0.18033688f;
  else if (i < 2048)  v = b[i - 1024];
  else                v = c[i - 2048];
  out[i] = v;
}

__global__ __launch_bounds__(256) void cast_f32_bf16(
    const float* __restrict__ in, bf16* __restrict__ out) {
  int i0 = (blockIdx.x * 256 + threadIdx.x) * 4;
  float4 f = *reinterpret_cast<const float4*>(in + i0);
  short* o = (short*)out + i0;
  o[0] = f2b(f.x); o[1] = f2b(f.y); o[2] = f2b(f.z); o[3] = f2b(f.w);
}

// ---------------------------------------------------------------------------
extern "C" void kernel_launch(void* const* d_in, const int* in_sizes, int n_in,
                              void* d_out, int out_size, void* d_ws, size_t ws_size,
                              hipStream_t stream) {
  (void)in_sizes; (void)n_in; (void)out_size; (void)ws_size;
  const float* x    = (const float*)d_in[0];
  const int*   mask = (const int*)d_in[1];
  const float* wq_w = (const float*)d_in[2];
  const float* wq_b = (const float*)d_in[3];
  const float* wk_w = (const float*)d_in[4];
  const float* wk_b = (const float*)d_in[5];
  const float* wv_w = (const float*)d_in[6];
  const float* wv_b = (const float*)d_in[7];
  const float* wo_w = (const float*)d_in[8];
  const float* wo_b = (const float*)d_in[9];
  const float* g1   = (const float*)d_in[10];
  const float* be1  = (const float*)d_in[11];
  const float* f1w  = (const float*)d_in[12];
  const float* f1b  = (const float*)d_in[13];
  const float* f2w  = (const float*)d_in[14];
  const float* f2b_ = (const float*)d_in[15];
  const float* g2   = (const float*)d_in[16];
  const float* be2  = (const float*)d_in[17];
  float* out = (float*)d_out;
  char* ws = (char*)d_ws;

  // ws layout (peak 48 MiB, time-shared):
  //  [0,24M)   QKV (ph2-3) -> PROJ fp32 [0,16M) (ph4-5) -> H [0,32M) (ph6-7)
  //  [24M,32M) Xbf (ph1-2) -> AO (ph3-4)
  //  [32M,40M) X1  (ph5-8)
  //  [40M,48M) WT  (transposed weights, per-phase)  + BQKV fp32 tail
  bf16*  QKV  = (bf16*)(ws + 0);
  bf16*  Xbf  = (bf16*)(ws + 25165824);
  bf16*  AO   = (bf16*)(ws + 25165824);
  float* PROJ = (float*)(ws + 0);
  bf16*  H    = (bf16*)(ws + 0);
  bf16*  X1   = (bf16*)(ws + 33554432);
  bf16*  WT   = (bf16*)(ws + 41943040);
  float* BQKV = (float*)(ws + 48234496);

  const float QSCALE = 0.18033688f;  // (1/sqrt(64)) * log2(e)

  dim3 tb(32, 8);
  // phase 1: casts + QKV weights (wq pre-scaled for exp2-direct softmax)
  cast_f32_bf16<<<dim3(4096), dim3(256), 0, stream>>>(x, Xbf);
  transpose_k<<<dim3(32, 32), tb, 0, stream>>>(wq_w, WT, 1024, 1024, QSCALE);
  transpose_k<<<dim3(32, 32), tb, 0, stream>>>(wk_w, WT + 1024 * 1024, 1024, 1024, 1.0f);
  transpose_k<<<dim3(32, 32), tb, 0, stream>>>(wv_w, WT + 2 * 1024 * 1024, 1024, 1024, 1.0f);
  concat3<<<dim3(12), dim3(256), 0, stream>>>(wq_b, wk_b, wv_b, BQKV);
  // phase 2: fused QKV projection — 128² BK=64 pipeline, 768 blocks
  gemm_bt128<<<dim3(24, 32), dim3(256), 0, stream>>>(Xbf, WT, BQKV, QKV, 1024, 3072, 0, 0);
  // phase 3: attention (512 blocks: 16 q-blocks x 32 bh, KVBLK=128)
  attn_kernel<<<dim3(16, 32), dim3(256), 0, stream>>>(QKV, mask, AO);
  // phase 4: output projection — BK=64 pipeline, split-K=2, fp32 atomic into PROJ
  transpose_k<<<dim3(32, 32), tb, 0, stream>>>(wo_w, WT, 1024, 1024, 1.0f);
  bias_init<<<dim3(4096), dim3(256), 0, stream>>>(wo_b, PROJ);
  gemm_pipe<<<dim3(8, 32, 2), dim3(256), 0, stream>>>(AO, WT, PROJ, 1024, 1024, 512);
  // phase 5: LN1 (a = PROJ fp32, xres = original fp32 x)
  ln_resid<<<dim3(4096), dim3(256), 0, stream>>>(PROJ, x, g1, be1, X1, 1, 1, 0);
  // phase 6: FFN up — 128² BK=64 pipeline, 1024 blocks
  transpose_k<<<dim3(128, 32), tb, 0, stream>>>(f1w, WT, 1024, 4096, 1.0f);
  gemm_bt128<<<dim3(32, 32), dim3(256), 0, stream>>>(X1, WT, f1b, H, 1024, 4096, 1, 0);
  // phase 7: FFN down — BK=64 pipeline, split-K=2, fp32 atomic straight into d_out
  transpose_k<<<dim3(32, 128), tb, 0, stream>>>(f2w, WT, 4096, 1024, 1.0f);
  bias_init<<<dim3(4096), dim3(256), 0, stream>>>(f2b_, out);
  gemm_pipe<<<dim3(8, 32, 2), dim3(256), 0, stream>>>(H, WT, out, 4096, 1024, 2048);
  // phase 8: LN2 in-place on d_out (fp32 a, bf16 xres, fp32 out)
  ln_resid<<<dim3(4096), dim3(256), 0, stream>>>(out, X1, g2, be2, out, 1, 0, 1);
}

// Round 18
// 418.323 us; speedup vs baseline: 1.0335x; 1.0335x over previous
//
#include <hip/hip_runtime.h>
#include <hip/hip_bf16.h>
#include <cstdint>
#include <cstddef>

using bf16 = __hip_bfloat16;
typedef __attribute__((ext_vector_type(8))) short short8v;   // MFMA A/B frag: 8 bf16
typedef __attribute__((ext_vector_type(4))) short short4v;   // 4 bf16 (b64 load/store)
typedef __attribute__((ext_vector_type(4))) float float4v;   // MFMA C/D frag

__device__ inline float b2f(short s) {
  union { float f; uint32_t u; } z; z.u = ((uint32_t)(uint16_t)s) << 16; return z.f;
}
__device__ inline short f2b(float f) {
  bf16 h = __float2bfloat16(f);
  return *reinterpret_cast<short*>(&h);
}

typedef const __attribute__((address_space(1))) uint32_t* gas1p;
typedef __attribute__((address_space(3))) uint32_t* las3p;
__device__ inline void gload_lds16(const void* g, void* l) {
  __builtin_amdgcn_global_load_lds((gas1p)g, (las3p)l, 16, 0, 0);
}

// T1 XCD swizzle. Round-11 PMC confirmed: co-locates panel-sharing blocks on
// one XCD's L2 (gemm_pipe FETCH dropped 135 MB -> 32.8 MB compulsory).
__device__ inline void xcd_swizzle(int& bx, int& by, int& bz) {
  const int gx = gridDim.x, gy = gridDim.y;
  const int nwg = gx * gy * gridDim.z;
  const int wgid = blockIdx.x + gx * (blockIdx.y + gy * blockIdx.z);
  const int swz = (wgid & 7) * (nwg >> 3) + (wgid >> 3);
  bx = swz % gx;
  by = (swz / gx) % gy;
  bz = swz / (gx * gy);
}

// ---------------------------------------------------------------------------
// 128²-tile GEMM for QKV/FF1: BK=64 as two BK=32 halves, double-buffered LDS,
// ONE barrier/iter, XCD swizzle; bias/ReLU/bf16 epilogue. LDS 64 KB ->
// 2 blocks/CU resident.
// ---------------------------------------------------------------------------
__global__ __launch_bounds__(256) void gemm_bt128(
    const bf16* __restrict__ A, const bf16* __restrict__ Bt,
    const float* __restrict__ bias, void* __restrict__ C,
    int K, int ldc, int relu_mode, int out_f32) {
  __shared__ __align__(16) bf16 As[2][2][128 * 32];  // [buf][half][tile]
  __shared__ __align__(16) bf16 Bs[2][2][128 * 32];
  const int tid = threadIdx.x;
  const int w = tid >> 6, lane = tid & 63;
  const int quad = lane >> 4, l16 = lane & 15;
  const int wrow = (w >> 1) * 64, wcol = (w & 1) * 64;
  int bx, by, bz;
  xcd_swizzle(bx, by, bz);
  const int mbase = by * 128, nbase = bx * 128;
  const int c0 = w * 128 + lane;           // chunk ids c0 and c0+64
  const int row0 = c0 >> 2, p0 = c0 & 3;
  const int row1 = (c0 + 64) >> 2, p1 = (c0 + 64) & 3;

  const bf16* ag0 = A + (size_t)(mbase + row0) * K + p0 * 8;
  const bf16* ag1 = A + (size_t)(mbase + row1) * K + p1 * 8;
  const bf16* bg0 = Bt + (size_t)(nbase + row0) * K + p0 * 8;
  const bf16* bg1 = Bt + (size_t)(nbase + row1) * K + p1 * 8;

  // stage 64-col tile t64 into buffer bi (two BK=32 halves)
  auto stage = [&](int t64, int bi) {
    const int ko = t64 * 64;
#pragma unroll
    for (int h = 0; h < 2; h++) {
      char* da = (char*)As + (size_t)(bi * 2 + h) * 8192 + w * 2048;
      char* db = (char*)Bs + (size_t)(bi * 2 + h) * 8192 + w * 2048;
      gload_lds16(ag0 + ko + h * 32, da);
      gload_lds16(ag1 + ko + h * 32, da + 1024);
      gload_lds16(bg0 + ko + h * 32, db);
      gload_lds16(bg1 + ko + h * 32, db + 1024);
    }
  };

  float4v acc[4][4];
  for (int i = 0; i < 4; i++)
    for (int j = 0; j < 4; j++) acc[i][j] = (float4v){0.f, 0.f, 0.f, 0.f};

  const int KT2 = K >> 6;
  // prologue: tile 0 -> buf 0
  stage(0, 0);
  __syncthreads();

  for (int kt = 0; kt < KT2; kt++) {
    const int pb = kt & 1;
    if (kt + 1 < KT2) stage(kt + 1, 1 - pb);  // issued early, drained at barrier

#pragma unroll
    for (int h = 0; h < 2; h++) {
      const bf16* Ah = &As[pb][h][0];
      const bf16* Bh = &Bs[pb][h][0];
      short8v a[4], b[4];
      for (int mt = 0; mt < 4; mt++)
        a[mt] = *reinterpret_cast<const short8v*>(Ah + (wrow + mt * 16 + l16) * 32 + quad * 8);
      for (int nt = 0; nt < 4; nt++)
        b[nt] = *reinterpret_cast<const short8v*>(Bh + (wcol + nt * 16 + l16) * 32 + quad * 8);
      for (int mt = 0; mt < 4; mt++)
        for (int nt = 0; nt < 4; nt++)
          acc[mt][nt] = __builtin_amdgcn_mfma_f32_16x16x32_bf16(a[mt], b[nt], acc[mt][nt], 0, 0, 0);
    }

    __syncthreads();  // drains vmcnt (next tile valid) + lgkm (reads done)
  }

  // epilogue: D row = quad*4+reg, col = lane&15
  for (int nt = 0; nt < 4; nt++) {
    int col = nbase + wcol + nt * 16 + l16;
    float bv = bias[col];
    for (int mt = 0; mt < 4; mt++) {
      int row = mbase + wrow + mt * 16 + quad * 4;
      for (int r = 0; r < 4; r++) {
        float v = acc[mt][nt][r] + bv;
        if (relu_mode) v = fmaxf(v, 0.f);
        size_t idx = (size_t)(row + r) * ldc + col;
        if (out_f32) ((float*)C)[idx] = v;
        else         ((short*)C)[idx] = f2b(v);
      }
    }
  }
}

// ---------------------------------------------------------------------------
// Pipelined split-K GEMM for WO/FF2. v4: BK=64 per barrier as two BK=32
// halves, double-buffered, one barrier/iter, + T1 XCD swizzle. Split-K FIXED
// at 2 (round-15: split-K=4 regressed via atomic contention at the LDS-capped
// 2 blocks/CU). blockIdx.z selects a K-slice; partial sums atomicAdd into
// fp32 C (bias pre-initialized).
// ---------------------------------------------------------------------------
__global__ __launch_bounds__(256) void gemm_pipe(
    const bf16* __restrict__ A, const bf16* __restrict__ Bt,
    float* __restrict__ C, int K, int ldc, int k_len) {
  __shared__ __align__(16) bf16 As[2][2][128 * 32];  // [buf][half][tile]
  __shared__ __align__(16) bf16 Bs[2][2][128 * 32];
  const int tid = threadIdx.x;
  const int w = tid >> 6, lane = tid & 63;
  const int quad = lane >> 4, l16 = lane & 15;
  const int wrow = (w >> 1) * 64, wcol = (w & 1) * 64;
  int bx, by, bz;
  xcd_swizzle(bx, by, bz);
  const int mbase = by * 128, nbase = bx * 128;
  const int c0 = w * 128 + lane;           // chunk ids c0 and c0+64
  const int row0 = c0 >> 2, p0 = c0 & 3;
  const int row1 = (c0 + 64) >> 2, p1 = (c0 + 64) & 3;
  const int kbase = bz * k_len;

  const bf16* ag0 = A + (size_t)(mbase + row0) * K + kbase + p0 * 8;
  const bf16* ag1 = A + (size_t)(mbase + row1) * K + kbase + p1 * 8;
  const bf16* bg0 = Bt + (size_t)(nbase + row0) * K + kbase + p0 * 8;
  const bf16* bg1 = Bt + (size_t)(nbase + row1) * K + kbase + p1 * 8;

  // stage 64-col tile t64 into buffer bi (two BK=32 halves)
  auto stage = [&](int t64, int bi) {
    const int ko = t64 * 64;
#pragma unroll
    for (int h = 0; h < 2; h++) {
      char* da = (char*)As + (size_t)(bi * 2 + h) * 8192 + w * 2048;
      char* db = (char*)Bs + (size_t)(bi * 2 + h) * 8192 + w * 2048;
      gload_lds16(ag0 + ko + h * 32, da);
      gload_lds16(ag1 + ko + h * 32, da + 1024);
      gload_lds16(bg0 + ko + h * 32, db);
      gload_lds16(bg1 + ko + h * 32, db + 1024);
    }
  };

  float4v acc[4][4];
  for (int i = 0; i < 4; i++)
    for (int j = 0; j < 4; j++) acc[i][j] = (float4v){0.f, 0.f, 0.f, 0.f};

  const int KT2 = k_len >> 6;
  // prologue: tile 0 -> buf 0
  stage(0, 0);
  __syncthreads();

  for (int kt = 0; kt < KT2; kt++) {
    const int pb = kt & 1;
    if (kt + 1 < KT2) stage(kt + 1, 1 - pb);  // issued early, drained at barrier

#pragma unroll
    for (int h = 0; h < 2; h++) {
      const bf16* Ah = &As[pb][h][0];
      const bf16* Bh = &Bs[pb][h][0];
      short8v a[4], b[4];
      for (int mt = 0; mt < 4; mt++)
        a[mt] = *reinterpret_cast<const short8v*>(Ah + (wrow + mt * 16 + l16) * 32 + quad * 8);
      for (int nt = 0; nt < 4; nt++)
        b[nt] = *reinterpret_cast<const short8v*>(Bh + (wcol + nt * 16 + l16) * 32 + quad * 8);
      for (int mt = 0; mt < 4; mt++)
        for (int nt = 0; nt < 4; nt++)
          acc[mt][nt] = __builtin_amdgcn_mfma_f32_16x16x32_bf16(a[mt], b[nt], acc[mt][nt], 0, 0, 0);
    }

    __syncthreads();  // drains vmcnt (next tile valid) + lgkm (reads done)
  }

  // epilogue: partial-sum atomicAdd (C pre-initialized with bias)
  for (int nt = 0; nt < 4; nt++) {
    int col = nbase + wcol + nt * 16 + l16;
    for (int mt = 0; mt < 4; mt++) {
      int row = mbase + wrow + mt * 16 + quad * 4;
      for (int r = 0; r < 4; r++)
        atomicAdd(&C[(size_t)(row + r) * ldc + col], acc[mt][nt][r]);
    }
  }
}

// C[row, 0..N) = bias[0..N), fp32. grid = rows, block 256, N = 1024.
__global__ __launch_bounds__(256) void bias_init(
    const float* __restrict__ bias, float* __restrict__ C) {
  int c = threadIdx.x * 4;
  float4 bv = *reinterpret_cast<const float4*>(bias + c);
  *reinterpret_cast<float4*>(C + (size_t)blockIdx.x * 1024 + c) = bv;
}

// ---------------------------------------------------------------------------
// Flash attention v10 (round-16 anchor config): 32 q/wave, 512 blocks,
// KVBLK=64 (two 32-kv subtiles per barrier) — 32 iterations. Round-17 probed
// KVBLK=128: VGPR 80->120 prefetch state + 66 KB LDS cost more than the 16
// saved barriers (60 -> 73 µs). KVBLK=64 is the measured interior optimum.
// ---------------------------------------------------------------------------
__global__ __launch_bounds__(256) void attn_kernel(
    const bf16* __restrict__ qkv, const int* __restrict__ mask,
    bf16* __restrict__ ao) {
  __shared__ __align__(16) short Vt[2][64 * 72];   // [buf][d][kv0..63], pitch 72
  __shared__ __align__(16) short Ks[2][64 * 64];   // [buf][kv][d], row-XOR-swizzled

  const int tid = threadIdx.x;
  const int w = tid >> 6, lane = tid & 63;
  const int quad = lane >> 4, l16 = lane & 15;
  const int bh = blockIdx.y, b = bh >> 4;
  const int row0 = bh * 128;                 // row base in qkv [4096,3072]
  const int qbase = blockIdx.x * 128 + w * 32;  // wave's 32 q rows
  const int kvp = tid & 15, dg = tid >> 4;   // V stager: kv rows 2kvp,2kvp+1; d 4dg..+3
  const int krow = tid >> 3, kc = tid & 7;   // K stager: rows krow & krow+32, chunk kc

  // Q fragments (B-operand of swapped QK^T); Q is pre-scaled by log2(e)/8
  short8v aq[2][2];
  for (int h = 0; h < 2; h++)
    for (int dh = 0; dh < 2; dh++) {
      int local = (qbase + h * 16 + l16) * 64 + dh * 32 + quad * 8;
      aq[h][dh] = *reinterpret_cast<const short8v*>(
          qkv + (size_t)(row0 + (local >> 10)) * 3072 + (local & 1023));
    }

  // K stage pointers (2 b128/thread cover the 64x64 tile)
  const bf16* pks0;
  {
    int local = krow * 64 + kc * 8;
    pks0 = qkv + (size_t)(row0 + (local >> 10)) * 3072 + (local & 1023) + 1024;
  }
  const bf16* pks1 = pks0 + 6144;
  // V stage pointers (2 kv rows x 4 d per thread, x2 subtiles)
  const bf16* pva;
  const bf16* pvb;
  {
    int la = (2 * kvp) * 64 + dg * 4;
    pva = qkv + (size_t)(row0 + (la >> 10)) * 3072 + (la & 1023) + 2048;
    int lb = (2 * kvp + 1) * 64 + dg * 4;
    pvb = qkv + (size_t)(row0 + (lb >> 10)) * 3072 + (lb & 1023) + 2048;
  }
  const bf16* pva2 = pva + 6144;
  const bf16* pvb2 = pvb + 6144;
  const int* pm = mask + b * 2048 + quad * 4;

  float4v o[2][4];
  for (int h = 0; h < 2; h++)
    for (int nt = 0; nt < 4; nt++) o[h][nt] = (float4v){0.f, 0.f, 0.f, 0.f};
  float4v lacc[2];
  lacc[0] = (float4v){0.f, 0.f, 0.f, 0.f};
  lacc[1] = (float4v){0.f, 0.f, 0.f, 0.f};
  short8v vone;
  for (int j = 0; j < 8; j++) vone[j] = (short)0x3F80;  // bf16 1.0 x8

  // prologue: load + stage tile 0 (64 kv rows)
  short8v kr0, kr1;
  short4v va, vb, va2, vb2;
  kr0 = *reinterpret_cast<const short8v*>(pks0);
  kr1 = *reinterpret_cast<const short8v*>(pks1);
  va  = *reinterpret_cast<const short4v*>(pva);
  vb  = *reinterpret_cast<const short4v*>(pvb);
  va2 = *reinterpret_cast<const short4v*>(pva2);
  vb2 = *reinterpret_cast<const short4v*>(pvb2);
  int4 mc0 = *reinterpret_cast<const int4*>(pm);
  int4 mc1 = *reinterpret_cast<const int4*>(pm + 16);
  int4 mc2 = *reinterpret_cast<const int4*>(pm + 32);
  int4 mc3 = *reinterpret_cast<const int4*>(pm + 48);
  pks0 += 12288; pks1 += 12288; pva += 12288; pvb += 12288;
  pva2 += 12288; pvb2 += 12288; pm += 64;
  {
    const int sw = (kc ^ (krow & 7)) << 3;
    *reinterpret_cast<short8v*>(&Ks[0][krow * 64 + sw]) = kr0;
    *reinterpret_cast<short8v*>(&Ks[0][(krow + 32) * 64 + sw]) = kr1;
    uint32_t* vt = reinterpret_cast<uint32_t*>(&Vt[0][0]);
    for (int i = 0; i < 4; i++) {
      vt[(dg * 4 + i) * 36 + kvp] =
          ((uint32_t)(uint16_t)vb[i] << 16) | (uint16_t)(uint16_t)va[i];
      vt[(dg * 4 + i) * 36 + 16 + kvp] =
          ((uint32_t)(uint16_t)vb2[i] << 16) | (uint16_t)(uint16_t)va2[i];
    }
  }
  __syncthreads();

  for (int it = 0; it < 32; it++) {
    const int pb = it & 1;
    short8v knr0, knr1;
    short4v vna, vnb, vna2, vnb2;
    int4 mn0, mn1, mn2, mn3;
    if (it < 31) {
      knr0 = *reinterpret_cast<const short8v*>(pks0);
      knr1 = *reinterpret_cast<const short8v*>(pks1);
      vna  = *reinterpret_cast<const short4v*>(pva);
      vnb  = *reinterpret_cast<const short4v*>(pvb);
      vna2 = *reinterpret_cast<const short4v*>(pva2);
      vnb2 = *reinterpret_cast<const short4v*>(pvb2);
      mn0 = *reinterpret_cast<const int4*>(pm);
      mn1 = *reinterpret_cast<const int4*>(pm + 16);
      mn2 = *reinterpret_cast<const int4*>(pm + 32);
      mn3 = *reinterpret_cast<const int4*>(pm + 48);
      pks0 += 12288; pks1 += 12288; pva += 12288; pvb += 12288;
      pva2 += 12288; pvb2 += 12288; pm += 64;
    }

#pragma unroll
    for (int sub = 0; sub < 2; sub++) {
      // K fragments from LDS (swizzled read: chunk (dh*4+quad) ^ (l16&7))
      short8v kc_[2][2];
      for (int s = 0; s < 2; s++)
        for (int dh = 0; dh < 2; dh++) {
          int rr = sub * 32 + s * 16 + l16;
          kc_[s][dh] = *reinterpret_cast<const short8v*>(
              &Ks[pb][rr * 64 + (((dh * 4 + quad) ^ (l16 & 7)) << 3)]);
        }

      float4v st[2][2];
      for (int s = 0; s < 2; s++)
        for (int h = 0; h < 2; h++) {
          float4v t = (float4v){0.f, 0.f, 0.f, 0.f};
          t = __builtin_amdgcn_mfma_f32_16x16x32_bf16(kc_[s][0], aq[h][0], t, 0, 0, 0);
          t = __builtin_amdgcn_mfma_f32_16x16x32_bf16(kc_[s][1], aq[h][1], t, 0, 0, 0);
          st[s][h] = t;
        }

      // softmax numerator + in-register P-fragment assembly (no LDS)
      short8v pf[2];
      for (int h = 0; h < 2; h++) {
        float ev[2][4];
        for (int s = 0; s < 2; s++) {
          int4 mv = sub ? (s ? mc3 : mc2) : (s ? mc1 : mc0);
          int mm[4] = {mv.x, mv.y, mv.z, mv.w};
          for (int r = 0; r < 4; r++) {
            float y = st[s][h][r];                    // already exp2-arg units
            y = (mm[r] == 0) ? -1.4427e-12f : y;      // faithful mask semantics
            ev[s][r] = __builtin_amdgcn_exp2f(y);
          }
        }
        uint32_t a0, a1, b0, b1;
        asm("v_cvt_pk_bf16_f32 %0, %1, %2" : "=v"(a0) : "v"(ev[0][0]), "v"(ev[0][1]));
        asm("v_cvt_pk_bf16_f32 %0, %1, %2" : "=v"(a1) : "v"(ev[0][2]), "v"(ev[0][3]));
        asm("v_cvt_pk_bf16_f32 %0, %1, %2" : "=v"(b0) : "v"(ev[1][0]), "v"(ev[1][1]));
        asm("v_cvt_pk_bf16_f32 %0, %1, %2" : "=v"(b1) : "v"(ev[1][2]), "v"(ev[1][3]));
        // halves: lanes<32 hold A-family (s=0), >=32 B-family (s=1)
        asm("v_permlane32_swap_b32 %0, %1" : "+v"(b0), "+v"(a0));
        asm("v_permlane16_swap_b32 %0, %1" : "+v"(b0), "+v"(a0));
        asm("v_permlane32_swap_b32 %0, %1" : "+v"(b1), "+v"(a1));
        asm("v_permlane16_swap_b32 %0, %1" : "+v"(b1), "+v"(a1));
        union { short8v s8; uint32_t u[4]; } pfu;
        pfu.u[0] = a0; pfu.u[1] = a1; pfu.u[2] = b0; pfu.u[3] = b1;
        pf[h] = pfu.s8;
      }

      for (int h = 0; h < 2; h++)
        lacc[h] = __builtin_amdgcn_mfma_f32_16x16x32_bf16(pf[h], vone, lacc[h], 0, 0, 0);
      for (int nt = 0; nt < 4; nt++) {
        short8v bv = *reinterpret_cast<const short8v*>(
            &Vt[pb][(nt * 16 + l16) * 72 + sub * 32 + quad * 8]);
        for (int h = 0; h < 2; h++)
          o[h][nt] = __builtin_amdgcn_mfma_f32_16x16x32_bf16(pf[h], bv, o[h][nt], 0, 0, 0);
      }
    }

    if (it < 31) {
      const int sw = (kc ^ (krow & 7)) << 3;
      *reinterpret_cast<short8v*>(&Ks[1 - pb][krow * 64 + sw]) = knr0;
      *reinterpret_cast<short8v*>(&Ks[1 - pb][(krow + 32) * 64 + sw]) = knr1;
      uint32_t* vt = reinterpret_cast<uint32_t*>(&Vt[1 - pb][0]);
      for (int i = 0; i < 4; i++) {
        vt[(dg * 4 + i) * 36 + kvp] =
            ((uint32_t)(uint16_t)vnb[i] << 16) | (uint16_t)(uint16_t)vna[i];
        vt[(dg * 4 + i) * 36 + 16 + kvp] =
            ((uint32_t)(uint16_t)vnb2[i] << 16) | (uint16_t)(uint16_t)vna2[i];
      }
      mc0 = mn0; mc1 = mn1; mc2 = mn2; mc3 = mn3;
    }
    __syncthreads();
  }

  // lacc[h][r] = rowsum(P) for q row quad*4+r (all 16 cols identical)
  for (int h = 0; h < 2; h++)
    for (int r = 0; r < 4; r++) {
      float linv = 1.0f / lacc[h][r];
      int qg = qbase + h * 16 + quad * 4 + r;
      for (int nt = 0; nt < 4; nt++) {
        int d = nt * 16 + l16;
        ao[(size_t)bh * 131072 + (size_t)qg * 64 + d] = __float2bfloat16(o[h][nt][r] * linv);
      }
    }
}

// ---------------------------------------------------------------------------
// out = LN(a + xres); unbiased std (ddof=1), /(std + 1e-12). One block / row.
// ---------------------------------------------------------------------------
__global__ __launch_bounds__(256) void ln_resid(
    const void* __restrict__ a, const void* __restrict__ xres,
    const float* __restrict__ gamma, const float* __restrict__ beta,
    void* __restrict__ out, int a_f32, int x_f32, int out_f32) {
  __shared__ float red[8];
  const int row = blockIdx.x, tid = threadIdx.x;
  const int w = tid >> 6, lane = tid & 63;
  const size_t base = (size_t)row * 1024;
  float v[4]; float sum = 0.f, ss = 0.f;
  for (int i = 0; i < 4; i++) {
    int c = tid + i * 256;
    float av = a_f32 ? ((const float*)a)[base + c] : b2f(((const short*)a)[base + c]);
    float xv = x_f32 ? ((const float*)xres)[base + c] : b2f(((const short*)xres)[base + c]);
    v[i] = av + xv;
    sum += v[i]; ss += v[i] * v[i];
  }
  for (int off = 1; off < 64; off <<= 1) {
    sum += __shfl_xor(sum, off);
    ss  += __shfl_xor(ss, off);
  }
  if (lane == 0) { red[w * 2] = sum; red[w * 2 + 1] = ss; }
  __syncthreads();
  sum = red[0] + red[2] + red[4] + red[6];
  ss  = red[1] + red[3] + red[5] + red[7];
  float mean = sum * (1.0f / 1024.0f);
  float var = (ss - 1024.0f * mean * mean) * (1.0f / 1023.0f);
  var = fmaxf(var, 0.f);
  float rden = 1.0f / (sqrtf(var) + 1e-12f);
  for (int i = 0; i < 4; i++) {
    int c = tid + i * 256;
    float y = gamma[c] * ((v[i] - mean) * rden) + beta[c];
    if (out_f32) ((float*)out)[base + c] = y;
    else         ((short*)out)[base + c] = f2b(y);
  }
}

// out(bf16)[c*R + r] = in(f32)[r*C + c] * scale; R,C % 32 == 0.
__global__ __launch_bounds__(256) void transpose_k(
    const float* __restrict__ in, bf16* __restrict__ out, int R, int C,
    float scale) {
  __shared__ short t[32][33];
  const int tx = threadIdx.x, ty = threadIdx.y;
  const int cb = blockIdx.x * 32, rb = blockIdx.y * 32;
  for (int j = 0; j < 4; j++)
    t[ty + j * 8][tx] = f2b(in[(size_t)(rb + ty + j * 8) * C + cb + tx] * scale);
  __syncthreads();
  for (int j = 0; j < 4; j++)
    ((short*)out)[(size_t)(cb + ty + j * 8) * R + rb + tx] = t[tx][ty + j * 8];
}

// q-bias scaled by log2(e)/8 to match the pre-scaled Q projection.
__global__ __launch_bounds__(256) void concat3(
    const float* __restrict__ a, const float* __restrict__ b,
    const float* __restrict__ c, float* __restrict__ out) {
  int i = blockIdx.x * 256 + threadIdx.x;  // grid 12 -> 3072
  float v;
  if (i < 1024)       v = a[i] * 0.18033688f;
  else if (i < 2048)  v = b[i - 1024];
  else                v = c[i - 2048];
  out[i] = v;
}

__global__ __launch_bounds__(256) void cast_f32_bf16(
    const float* __restrict__ in, bf16* __restrict__ out) {
  int i0 = (blockIdx.x * 256 + threadIdx.x) * 4;
  float4 f = *reinterpret_cast<const float4*>(in + i0);
  short* o = (short*)out + i0;
  o[0] = f2b(f.x); o[1] = f2b(f.y); o[2] = f2b(f.z); o[3] = f2b(f.w);
}

// ---------------------------------------------------------------------------
extern "C" void kernel_launch(void* const* d_in, const int* in_sizes, int n_in,
                              void* d_out, int out_size, void* d_ws, size_t ws_size,
                              hipStream_t stream) {
  (void)in_sizes; (void)n_in; (void)out_size; (void)ws_size;
  const float* x    = (const float*)d_in[0];
  const int*   mask = (const int*)d_in[1];
  const float* wq_w = (const float*)d_in[2];
  const float* wq_b = (const float*)d_in[3];
  const float* wk_w = (const float*)d_in[4];
  const float* wk_b = (const float*)d_in[5];
  const float* wv_w = (const float*)d_in[6];
  const float* wv_b = (const float*)d_in[7];
  const float* wo_w = (const float*)d_in[8];
  const float* wo_b = (const float*)d_in[9];
  const float* g1   = (const float*)d_in[10];
  const float* be1  = (const float*)d_in[11];
  const float* f1w  = (const float*)d_in[12];
  const float* f1b  = (const float*)d_in[13];
  const float* f2w  = (const float*)d_in[14];
  const float* f2b_ = (const float*)d_in[15];
  const float* g2   = (const float*)d_in[16];
  const float* be2  = (const float*)d_in[17];
  float* out = (float*)d_out;
  char* ws = (char*)d_ws;

  // ws layout (peak 48 MiB, time-shared):
  //  [0,24M)   QKV (ph2-3) -> PROJ fp32 [0,16M) (ph4-5) -> H [0,32M) (ph6-7)
  //  [24M,32M) Xbf (ph1-2) -> AO (ph3-4)
  //  [32M,40M) X1  (ph5-8)
  //  [40M,48M) WT  (transposed weights, per-phase)  + BQKV fp32 tail
  bf16*  QKV  = (bf16*)(ws + 0);
  bf16*  Xbf  = (bf16*)(ws + 25165824);
  bf16*  AO   = (bf16*)(ws + 25165824);
  float* PROJ = (float*)(ws + 0);
  bf16*  H    = (bf16*)(ws + 0);
  bf16*  X1   = (bf16*)(ws + 33554432);
  bf16*  WT   = (bf16*)(ws + 41943040);
  float* BQKV = (float*)(ws + 48234496);

  const float QSCALE = 0.18033688f;  // (1/sqrt(64)) * log2(e)

  dim3 tb(32, 8);
  // phase 1: casts + QKV weights (wq pre-scaled for exp2-direct softmax)
  cast_f32_bf16<<<dim3(4096), dim3(256), 0, stream>>>(x, Xbf);
  transpose_k<<<dim3(32, 32), tb, 0, stream>>>(wq_w, WT, 1024, 1024, QSCALE);
  transpose_k<<<dim3(32, 32), tb, 0, stream>>>(wk_w, WT + 1024 * 1024, 1024, 1024, 1.0f);
  transpose_k<<<dim3(32, 32), tb, 0, stream>>>(wv_w, WT + 2 * 1024 * 1024, 1024, 1024, 1.0f);
  concat3<<<dim3(12), dim3(256), 0, stream>>>(wq_b, wk_b, wv_b, BQKV);
  // phase 2: fused QKV projection — 128² BK=64 pipeline, 768 blocks
  gemm_bt128<<<dim3(24, 32), dim3(256), 0, stream>>>(Xbf, WT, BQKV, QKV, 1024, 3072, 0, 0);
  // phase 3: attention (512 blocks: 16 q-blocks x 32 bh, KVBLK=64)
  attn_kernel<<<dim3(16, 32), dim3(256), 0, stream>>>(QKV, mask, AO);
  // phase 4: output projection — BK=64 pipeline, split-K=2, fp32 atomic into PROJ
  transpose_k<<<dim3(32, 32), tb, 0, stream>>>(wo_w, WT, 1024, 1024, 1.0f);
  bias_init<<<dim3(4096), dim3(256), 0, stream>>>(wo_b, PROJ);
  gemm_pipe<<<dim3(8, 32, 2), dim3(256), 0, stream>>>(AO, WT, PROJ, 1024, 1024, 512);
  // phase 5: LN1 (a = PROJ fp32, xres = original fp32 x)
  ln_resid<<<dim3(4096), dim3(256), 0, stream>>>(PROJ, x, g1, be1, X1, 1, 1, 0);
  // phase 6: FFN up — 128² BK=64 pipeline, 1024 blocks
  transpose_k<<<dim3(128, 32), tb, 0, stream>>>(f1w, WT, 1024, 4096, 1.0f);
  gemm_bt128<<<dim3(32, 32), dim3(256), 0, stream>>>(X1, WT, f1b, H, 1024, 4096, 1, 0);
  // phase 7: FFN down — BK=64 pipeline, split-K=2, fp32 atomic straight into d_out
  transpose_k<<<dim3(32, 128), tb, 0, stream>>>(f2w, WT, 4096, 1024, 1.0f);
  bias_init<<<dim3(4096), dim3(256), 0, stream>>>(f2b_, out);
  gemm_pipe<<<dim3(8, 32, 2), dim3(256), 0, stream>>>(H, WT, out, 4096, 1024, 2048);
  // phase 8: LN2 in-place on d_out (fp32 a, bf16 xres, fp32 out)
  ln_resid<<<dim3(4096), dim3(256), 0, stream>>>(out, X1, g2, be2, out, 1, 0, 1);
}

// Round 19
// 405.598 us; speedup vs baseline: 1.0659x; 1.0314x over previous
//
#include <hip/hip_runtime.h>
#include <hip/hip_bf16.h>
#include <cstdint>
#include <cstddef>

using bf16 = __hip_bfloat16;
typedef __attribute__((ext_vector_type(8))) short short8v;   // MFMA A/B frag: 8 bf16
typedef __attribute__((ext_vector_type(4))) short short4v;   // 4 bf16 (b64 load/store)
typedef __attribute__((ext_vector_type(4))) float float4v;   // MFMA C/D frag

__device__ inline float b2f(short s) {
  union { float f; uint32_t u; } z; z.u = ((uint32_t)(uint16_t)s) << 16; return z.f;
}
__device__ inline short f2b(float f) {
  bf16 h = __float2bfloat16(f);
  return *reinterpret_cast<short*>(&h);
}

typedef const __attribute__((address_space(1))) uint32_t* gas1p;
typedef __attribute__((address_space(3))) uint32_t* las3p;
__device__ inline void gload_lds16(const void* g, void* l) {
  __builtin_amdgcn_global_load_lds((gas1p)g, (las3p)l, 16, 0, 0);
}

// T1 XCD swizzle. Round-11 PMC confirmed: co-locates panel-sharing blocks on
// one XCD's L2 (gemm_pipe FETCH dropped 135 MB -> 32.8 MB compulsory).
__device__ inline void xcd_swizzle(int& bx, int& by, int& bz) {
  const int gx = gridDim.x, gy = gridDim.y;
  const int nwg = gx * gy * gridDim.z;
  const int wgid = blockIdx.x + gx * (blockIdx.y + gy * blockIdx.z);
  const int swz = (wgid & 7) * (nwg >> 3) + (wgid >> 3);
  bx = swz % gx;
  by = (swz / gx) % gy;
  bz = swz / (gx * gy);
}

// ---------------------------------------------------------------------------
// 128²-tile GEMM for QKV/FF1: BK=64 as two BK=32 halves, double-buffered LDS,
// ONE barrier/iter, XCD swizzle; bias/ReLU/bf16 epilogue. LDS 64 KB ->
// 2 blocks/CU resident.
// ---------------------------------------------------------------------------
__global__ __launch_bounds__(256) void gemm_bt128(
    const bf16* __restrict__ A, const bf16* __restrict__ Bt,
    const float* __restrict__ bias, void* __restrict__ C,
    int K, int ldc, int relu_mode, int out_f32) {
  __shared__ __align__(16) bf16 As[2][2][128 * 32];  // [buf][half][tile]
  __shared__ __align__(16) bf16 Bs[2][2][128 * 32];
  const int tid = threadIdx.x;
  const int w = tid >> 6, lane = tid & 63;
  const int quad = lane >> 4, l16 = lane & 15;
  const int wrow = (w >> 1) * 64, wcol = (w & 1) * 64;
  int bx, by, bz;
  xcd_swizzle(bx, by, bz);
  const int mbase = by * 128, nbase = bx * 128;
  const int c0 = w * 128 + lane;           // chunk ids c0 and c0+64
  const int row0 = c0 >> 2, p0 = c0 & 3;
  const int row1 = (c0 + 64) >> 2, p1 = (c0 + 64) & 3;

  const bf16* ag0 = A + (size_t)(mbase + row0) * K + p0 * 8;
  const bf16* ag1 = A + (size_t)(mbase + row1) * K + p1 * 8;
  const bf16* bg0 = Bt + (size_t)(nbase + row0) * K + p0 * 8;
  const bf16* bg1 = Bt + (size_t)(nbase + row1) * K + p1 * 8;

  // stage 64-col tile t64 into buffer bi (two BK=32 halves)
  auto stage = [&](int t64, int bi) {
    const int ko = t64 * 64;
#pragma unroll
    for (int h = 0; h < 2; h++) {
      char* da = (char*)As + (size_t)(bi * 2 + h) * 8192 + w * 2048;
      char* db = (char*)Bs + (size_t)(bi * 2 + h) * 8192 + w * 2048;
      gload_lds16(ag0 + ko + h * 32, da);
      gload_lds16(ag1 + ko + h * 32, da + 1024);
      gload_lds16(bg0 + ko + h * 32, db);
      gload_lds16(bg1 + ko + h * 32, db + 1024);
    }
  };

  float4v acc[4][4];
  for (int i = 0; i < 4; i++)
    for (int j = 0; j < 4; j++) acc[i][j] = (float4v){0.f, 0.f, 0.f, 0.f};

  const int KT2 = K >> 6;
  // prologue: tile 0 -> buf 0
  stage(0, 0);
  __syncthreads();

  for (int kt = 0; kt < KT2; kt++) {
    const int pb = kt & 1;
    if (kt + 1 < KT2) stage(kt + 1, 1 - pb);  // issued early, drained at barrier

#pragma unroll
    for (int h = 0; h < 2; h++) {
      const bf16* Ah = &As[pb][h][0];
      const bf16* Bh = &Bs[pb][h][0];
      short8v a[4], b[4];
      for (int mt = 0; mt < 4; mt++)
        a[mt] = *reinterpret_cast<const short8v*>(Ah + (wrow + mt * 16 + l16) * 32 + quad * 8);
      for (int nt = 0; nt < 4; nt++)
        b[nt] = *reinterpret_cast<const short8v*>(Bh + (wcol + nt * 16 + l16) * 32 + quad * 8);
      for (int mt = 0; mt < 4; mt++)
        for (int nt = 0; nt < 4; nt++)
          acc[mt][nt] = __builtin_amdgcn_mfma_f32_16x16x32_bf16(a[mt], b[nt], acc[mt][nt], 0, 0, 0);
    }

    __syncthreads();  // drains vmcnt (next tile valid) + lgkm (reads done)
  }

  // epilogue: D row = quad*4+reg, col = lane&15
  for (int nt = 0; nt < 4; nt++) {
    int col = nbase + wcol + nt * 16 + l16;
    float bv = bias[col];
    for (int mt = 0; mt < 4; mt++) {
      int row = mbase + wrow + mt * 16 + quad * 4;
      for (int r = 0; r < 4; r++) {
        float v = acc[mt][nt][r] + bv;
        if (relu_mode) v = fmaxf(v, 0.f);
        size_t idx = (size_t)(row + r) * ldc + col;
        if (out_f32) ((float*)C)[idx] = v;
        else         ((short*)C)[idx] = f2b(v);
      }
    }
  }
}

// ---------------------------------------------------------------------------
// Pipelined split-K GEMM for WO/FF2. v4: BK=64 per barrier as two BK=32
// halves, double-buffered, one barrier/iter, + T1 XCD swizzle. Split-K FIXED
// at 2 (round-15: split-K=4 regressed via atomic contention at the LDS-capped
// 2 blocks/CU). blockIdx.z selects a K-slice; partial sums atomicAdd into
// fp32 C (bias pre-initialized).
// ---------------------------------------------------------------------------
__global__ __launch_bounds__(256) void gemm_pipe(
    const bf16* __restrict__ A, const bf16* __restrict__ Bt,
    float* __restrict__ C, int K, int ldc, int k_len) {
  __shared__ __align__(16) bf16 As[2][2][128 * 32];  // [buf][half][tile]
  __shared__ __align__(16) bf16 Bs[2][2][128 * 32];
  const int tid = threadIdx.x;
  const int w = tid >> 6, lane = tid & 63;
  const int quad = lane >> 4, l16 = lane & 15;
  const int wrow = (w >> 1) * 64, wcol = (w & 1) * 64;
  int bx, by, bz;
  xcd_swizzle(bx, by, bz);
  const int mbase = by * 128, nbase = bx * 128;
  const int c0 = w * 128 + lane;           // chunk ids c0 and c0+64
  const int row0 = c0 >> 2, p0 = c0 & 3;
  const int row1 = (c0 + 64) >> 2, p1 = (c0 + 64) & 3;
  const int kbase = bz * k_len;

  const bf16* ag0 = A + (size_t)(mbase + row0) * K + kbase + p0 * 8;
  const bf16* ag1 = A + (size_t)(mbase + row1) * K + kbase + p1 * 8;
  const bf16* bg0 = Bt + (size_t)(nbase + row0) * K + kbase + p0 * 8;
  const bf16* bg1 = Bt + (size_t)(nbase + row1) * K + kbase + p1 * 8;

  // stage 64-col tile t64 into buffer bi (two BK=32 halves)
  auto stage = [&](int t64, int bi) {
    const int ko = t64 * 64;
#pragma unroll
    for (int h = 0; h < 2; h++) {
      char* da = (char*)As + (size_t)(bi * 2 + h) * 8192 + w * 2048;
      char* db = (char*)Bs + (size_t)(bi * 2 + h) * 8192 + w * 2048;
      gload_lds16(ag0 + ko + h * 32, da);
      gload_lds16(ag1 + ko + h * 32, da + 1024);
      gload_lds16(bg0 + ko + h * 32, db);
      gload_lds16(bg1 + ko + h * 32, db + 1024);
    }
  };

  float4v acc[4][4];
  for (int i = 0; i < 4; i++)
    for (int j = 0; j < 4; j++) acc[i][j] = (float4v){0.f, 0.f, 0.f, 0.f};

  const int KT2 = k_len >> 6;
  // prologue: tile 0 -> buf 0
  stage(0, 0);
  __syncthreads();

  for (int kt = 0; kt < KT2; kt++) {
    const int pb = kt & 1;
    if (kt + 1 < KT2) stage(kt + 1, 1 - pb);  // issued early, drained at barrier

#pragma unroll
    for (int h = 0; h < 2; h++) {
      const bf16* Ah = &As[pb][h][0];
      const bf16* Bh = &Bs[pb][h][0];
      short8v a[4], b[4];
      for (int mt = 0; mt < 4; mt++)
        a[mt] = *reinterpret_cast<const short8v*>(Ah + (wrow + mt * 16 + l16) * 32 + quad * 8);
      for (int nt = 0; nt < 4; nt++)
        b[nt] = *reinterpret_cast<const short8v*>(Bh + (wcol + nt * 16 + l16) * 32 + quad * 8);
      for (int mt = 0; mt < 4; mt++)
        for (int nt = 0; nt < 4; nt++)
          acc[mt][nt] = __builtin_amdgcn_mfma_f32_16x16x32_bf16(a[mt], b[nt], acc[mt][nt], 0, 0, 0);
    }

    __syncthreads();  // drains vmcnt (next tile valid) + lgkm (reads done)
  }

  // epilogue: partial-sum atomicAdd (C pre-initialized with bias)
  for (int nt = 0; nt < 4; nt++) {
    int col = nbase + wcol + nt * 16 + l16;
    for (int mt = 0; mt < 4; mt++) {
      int row = mbase + wrow + mt * 16 + quad * 4;
      for (int r = 0; r < 4; r++)
        atomicAdd(&C[(size_t)(row + r) * ldc + col], acc[mt][nt][r]);
    }
  }
}

// ---------------------------------------------------------------------------
// Flash attention v10 (round-16 anchor config): 32 q/wave, 512 blocks,
// KVBLK=64 (two 32-kv subtiles per barrier) — 32 iterations. KVBLK=64 is the
// measured interior optimum (32: +15 µs, 128: +13 µs).
// ---------------------------------------------------------------------------
__global__ __launch_bounds__(256) void attn_kernel(
    const bf16* __restrict__ qkv, const int* __restrict__ mask,
    bf16* __restrict__ ao) {
  __shared__ __align__(16) short Vt[2][64 * 72];   // [buf][d][kv0..63], pitch 72
  __shared__ __align__(16) short Ks[2][64 * 64];   // [buf][kv][d], row-XOR-swizzled

  const int tid = threadIdx.x;
  const int w = tid >> 6, lane = tid & 63;
  const int quad = lane >> 4, l16 = lane & 15;
  const int bh = blockIdx.y, b = bh >> 4;
  const int row0 = bh * 128;                 // row base in qkv [4096,3072]
  const int qbase = blockIdx.x * 128 + w * 32;  // wave's 32 q rows
  const int kvp = tid & 15, dg = tid >> 4;   // V stager: kv rows 2kvp,2kvp+1; d 4dg..+3
  const int krow = tid >> 3, kc = tid & 7;   // K stager: rows krow & krow+32, chunk kc

  // Q fragments (B-operand of swapped QK^T); Q is pre-scaled by log2(e)/8
  short8v aq[2][2];
  for (int h = 0; h < 2; h++)
    for (int dh = 0; dh < 2; dh++) {
      int local = (qbase + h * 16 + l16) * 64 + dh * 32 + quad * 8;
      aq[h][dh] = *reinterpret_cast<const short8v*>(
          qkv + (size_t)(row0 + (local >> 10)) * 3072 + (local & 1023));
    }

  // K stage pointers (2 b128/thread cover the 64x64 tile)
  const bf16* pks0;
  {
    int local = krow * 64 + kc * 8;
    pks0 = qkv + (size_t)(row0 + (local >> 10)) * 3072 + (local & 1023) + 1024;
  }
  const bf16* pks1 = pks0 + 6144;
  // V stage pointers (2 kv rows x 4 d per thread, x2 subtiles)
  const bf16* pva;
  const bf16* pvb;
  {
    int la = (2 * kvp) * 64 + dg * 4;
    pva = qkv + (size_t)(row0 + (la >> 10)) * 3072 + (la & 1023) + 2048;
    int lb = (2 * kvp + 1) * 64 + dg * 4;
    pvb = qkv + (size_t)(row0 + (lb >> 10)) * 3072 + (lb & 1023) + 2048;
  }
  const bf16* pva2 = pva + 6144;
  const bf16* pvb2 = pvb + 6144;
  const int* pm = mask + b * 2048 + quad * 4;

  float4v o[2][4];
  for (int h = 0; h < 2; h++)
    for (int nt = 0; nt < 4; nt++) o[h][nt] = (float4v){0.f, 0.f, 0.f, 0.f};
  float4v lacc[2];
  lacc[0] = (float4v){0.f, 0.f, 0.f, 0.f};
  lacc[1] = (float4v){0.f, 0.f, 0.f, 0.f};
  short8v vone;
  for (int j = 0; j < 8; j++) vone[j] = (short)0x3F80;  // bf16 1.0 x8

  // prologue: load + stage tile 0 (64 kv rows)
  short8v kr0, kr1;
  short4v va, vb, va2, vb2;
  kr0 = *reinterpret_cast<const short8v*>(pks0);
  kr1 = *reinterpret_cast<const short8v*>(pks1);
  va  = *reinterpret_cast<const short4v*>(pva);
  vb  = *reinterpret_cast<const short4v*>(pvb);
  va2 = *reinterpret_cast<const short4v*>(pva2);
  vb2 = *reinterpret_cast<const short4v*>(pvb2);
  int4 mc0 = *reinterpret_cast<const int4*>(pm);
  int4 mc1 = *reinterpret_cast<const int4*>(pm + 16);
  int4 mc2 = *reinterpret_cast<const int4*>(pm + 32);
  int4 mc3 = *reinterpret_cast<const int4*>(pm + 48);
  pks0 += 12288; pks1 += 12288; pva += 12288; pvb += 12288;
  pva2 += 12288; pvb2 += 12288; pm += 64;
  {
    const int sw = (kc ^ (krow & 7)) << 3;
    *reinterpret_cast<short8v*>(&Ks[0][krow * 64 + sw]) = kr0;
    *reinterpret_cast<short8v*>(&Ks[0][(krow + 32) * 64 + sw]) = kr1;
    uint32_t* vt = reinterpret_cast<uint32_t*>(&Vt[0][0]);
    for (int i = 0; i < 4; i++) {
      vt[(dg * 4 + i) * 36 + kvp] =
          ((uint32_t)(uint16_t)vb[i] << 16) | (uint16_t)(uint16_t)va[i];
      vt[(dg * 4 + i) * 36 + 16 + kvp] =
          ((uint32_t)(uint16_t)vb2[i] << 16) | (uint16_t)(uint16_t)va2[i];
    }
  }
  __syncthreads();

  for (int it = 0; it < 32; it++) {
    const int pb = it & 1;
    short8v knr0, knr1;
    short4v vna, vnb, vna2, vnb2;
    int4 mn0, mn1, mn2, mn3;
    if (it < 31) {
      knr0 = *reinterpret_cast<const short8v*>(pks0);
      knr1 = *reinterpret_cast<const short8v*>(pks1);
      vna  = *reinterpret_cast<const short4v*>(pva);
      vnb  = *reinterpret_cast<const short4v*>(pvb);
      vna2 = *reinterpret_cast<const short4v*>(pva2);
      vnb2 = *reinterpret_cast<const short4v*>(pvb2);
      mn0 = *reinterpret_cast<const int4*>(pm);
      mn1 = *reinterpret_cast<const int4*>(pm + 16);
      mn2 = *reinterpret_cast<const int4*>(pm + 32);
      mn3 = *reinterpret_cast<const int4*>(pm + 48);
      pks0 += 12288; pks1 += 12288; pva += 12288; pvb += 12288;
      pva2 += 12288; pvb2 += 12288; pm += 64;
    }

#pragma unroll
    for (int sub = 0; sub < 2; sub++) {
      // K fragments from LDS (swizzled read: chunk (dh*4+quad) ^ (l16&7))
      short8v kc_[2][2];
      for (int s = 0; s < 2; s++)
        for (int dh = 0; dh < 2; dh++) {
          int rr = sub * 32 + s * 16 + l16;
          kc_[s][dh] = *reinterpret_cast<const short8v*>(
              &Ks[pb][rr * 64 + (((dh * 4 + quad) ^ (l16 & 7)) << 3)]);
        }

      float4v st[2][2];
      for (int s = 0; s < 2; s++)
        for (int h = 0; h < 2; h++) {
          float4v t = (float4v){0.f, 0.f, 0.f, 0.f};
          t = __builtin_amdgcn_mfma_f32_16x16x32_bf16(kc_[s][0], aq[h][0], t, 0, 0, 0);
          t = __builtin_amdgcn_mfma_f32_16x16x32_bf16(kc_[s][1], aq[h][1], t, 0, 0, 0);
          st[s][h] = t;
        }

      // softmax numerator + in-register P-fragment assembly (no LDS)
      short8v pf[2];
      for (int h = 0; h < 2; h++) {
        float ev[2][4];
        for (int s = 0; s < 2; s++) {
          int4 mv = sub ? (s ? mc3 : mc2) : (s ? mc1 : mc0);
          int mm[4] = {mv.x, mv.y, mv.z, mv.w};
          for (int r = 0; r < 4; r++) {
            float y = st[s][h][r];                    // already exp2-arg units
            y = (mm[r] == 0) ? -1.4427e-12f : y;      // faithful mask semantics
            ev[s][r] = __builtin_amdgcn_exp2f(y);
          }
        }
        uint32_t a0, a1, b0, b1;
        asm("v_cvt_pk_bf16_f32 %0, %1, %2" : "=v"(a0) : "v"(ev[0][0]), "v"(ev[0][1]));
        asm("v_cvt_pk_bf16_f32 %0, %1, %2" : "=v"(a1) : "v"(ev[0][2]), "v"(ev[0][3]));
        asm("v_cvt_pk_bf16_f32 %0, %1, %2" : "=v"(b0) : "v"(ev[1][0]), "v"(ev[1][1]));
        asm("v_cvt_pk_bf16_f32 %0, %1, %2" : "=v"(b1) : "v"(ev[1][2]), "v"(ev[1][3]));
        // halves: lanes<32 hold A-family (s=0), >=32 B-family (s=1)
        asm("v_permlane32_swap_b32 %0, %1" : "+v"(b0), "+v"(a0));
        asm("v_permlane16_swap_b32 %0, %1" : "+v"(b0), "+v"(a0));
        asm("v_permlane32_swap_b32 %0, %1" : "+v"(b1), "+v"(a1));
        asm("v_permlane16_swap_b32 %0, %1" : "+v"(b1), "+v"(a1));
        union { short8v s8; uint32_t u[4]; } pfu;
        pfu.u[0] = a0; pfu.u[1] = a1; pfu.u[2] = b0; pfu.u[3] = b1;
        pf[h] = pfu.s8;
      }

      for (int h = 0; h < 2; h++)
        lacc[h] = __builtin_amdgcn_mfma_f32_16x16x32_bf16(pf[h], vone, lacc[h], 0, 0, 0);
      for (int nt = 0; nt < 4; nt++) {
        short8v bv = *reinterpret_cast<const short8v*>(
            &Vt[pb][(nt * 16 + l16) * 72 + sub * 32 + quad * 8]);
        for (int h = 0; h < 2; h++)
          o[h][nt] = __builtin_amdgcn_mfma_f32_16x16x32_bf16(pf[h], bv, o[h][nt], 0, 0, 0);
      }
    }

    if (it < 31) {
      const int sw = (kc ^ (krow & 7)) << 3;
      *reinterpret_cast<short8v*>(&Ks[1 - pb][krow * 64 + sw]) = knr0;
      *reinterpret_cast<short8v*>(&Ks[1 - pb][(krow + 32) * 64 + sw]) = knr1;
      uint32_t* vt = reinterpret_cast<uint32_t*>(&Vt[1 - pb][0]);
      for (int i = 0; i < 4; i++) {
        vt[(dg * 4 + i) * 36 + kvp] =
            ((uint32_t)(uint16_t)vnb[i] << 16) | (uint16_t)(uint16_t)vna[i];
        vt[(dg * 4 + i) * 36 + 16 + kvp] =
            ((uint32_t)(uint16_t)vnb2[i] << 16) | (uint16_t)(uint16_t)vna2[i];
      }
      mc0 = mn0; mc1 = mn1; mc2 = mn2; mc3 = mn3;
    }
    __syncthreads();
  }

  // lacc[h][r] = rowsum(P) for q row quad*4+r (all 16 cols identical)
  for (int h = 0; h < 2; h++)
    for (int r = 0; r < 4; r++) {
      float linv = 1.0f / lacc[h][r];
      int qg = qbase + h * 16 + quad * 4 + r;
      for (int nt = 0; nt < 4; nt++) {
        int d = nt * 16 + l16;
        ao[(size_t)bh * 131072 + (size_t)qg * 64 + d] = __float2bfloat16(o[h][nt][r] * linv);
      }
    }
}

// ---------------------------------------------------------------------------
// out = LN(a + xres); unbiased std (ddof=1), /(std + 1e-12). One block / row.
// ---------------------------------------------------------------------------
__global__ __launch_bounds__(256) void ln_resid(
    const void* __restrict__ a, const void* __restrict__ xres,
    const float* __restrict__ gamma, const float* __restrict__ beta,
    void* __restrict__ out, int a_f32, int x_f32, int out_f32) {
  __shared__ float red[8];
  const int row = blockIdx.x, tid = threadIdx.x;
  const int w = tid >> 6, lane = tid & 63;
  const size_t base = (size_t)row * 1024;
  float v[4]; float sum = 0.f, ss = 0.f;
  for (int i = 0; i < 4; i++) {
    int c = tid + i * 256;
    float av = a_f32 ? ((const float*)a)[base + c] : b2f(((const short*)a)[base + c]);
    float xv = x_f32 ? ((const float*)xres)[base + c] : b2f(((const short*)xres)[base + c]);
    v[i] = av + xv;
    sum += v[i]; ss += v[i] * v[i];
  }
  for (int off = 1; off < 64; off <<= 1) {
    sum += __shfl_xor(sum, off);
    ss  += __shfl_xor(ss, off);
  }
  if (lane == 0) { red[w * 2] = sum; red[w * 2 + 1] = ss; }
  __syncthreads();
  sum = red[0] + red[2] + red[4] + red[6];
  ss  = red[1] + red[3] + red[5] + red[7];
  float mean = sum * (1.0f / 1024.0f);
  float var = (ss - 1024.0f * mean * mean) * (1.0f / 1023.0f);
  var = fmaxf(var, 0.f);
  float rden = 1.0f / (sqrtf(var) + 1e-12f);
  for (int i = 0; i < 4; i++) {
    int c = tid + i * 256;
    float y = gamma[c] * ((v[i] - mean) * rden) + beta[c];
    if (out_f32) ((float*)out)[base + c] = y;
    else         ((short*)out)[base + c] = f2b(y);
  }
}

// ---------------------------------------------------------------------------
// Transpose body (shared by the fused prep kernels): out(bf16)[c*R + r] =
// in(f32)[r*C + c] * scale, 32x32 tile at (cb, rb). Block (32,8).
// ---------------------------------------------------------------------------
__device__ inline void transpose_tile(
    const float* __restrict__ in, bf16* __restrict__ out, int R, int C,
    float scale, int cb, int rb) {
  __shared__ short t[32][33];
  const int tx = threadIdx.x, ty = threadIdx.y;
  for (int j = 0; j < 4; j++)
    t[ty + j * 8][tx] = f2b(in[(size_t)(rb + ty + j * 8) * C + cb + tx] * scale);
  __syncthreads();
  for (int j = 0; j < 4; j++)
    ((short*)out)[(size_t)(cb + ty + j * 8) * R + rb + tx] = t[tx][ty + j * 8];
}

// standalone transpose (f1w — nothing to fuse with)
__global__ __launch_bounds__(256) void transpose_k(
    const float* __restrict__ in, bf16* __restrict__ out, int R, int C,
    float scale) {
  transpose_tile(in, out, R, C, scale, blockIdx.x * 32, blockIdx.y * 32);
}

// ---------------------------------------------------------------------------
// Fused phase-1 prep (round 19: dispatch consolidation, 5 kernels -> 1).
// grid (32,32,4), block (32,8):
//  z=0..2: transpose wq/wk/wv -> WT+z*1M (wq scaled by QSCALE)
//  z=3:    cast x f32->bf16 (1024 flat blocks x 4096 elems) + concat3 (blk 0)
// ---------------------------------------------------------------------------
__global__ __launch_bounds__(256) void prep_qkv(
    const float* __restrict__ wq_w, const float* __restrict__ wk_w,
    const float* __restrict__ wv_w, bf16* __restrict__ WT,
    const float* __restrict__ x, bf16* __restrict__ Xbf,
    const float* __restrict__ wq_b, const float* __restrict__ wk_b,
    const float* __restrict__ wv_b, float* __restrict__ BQKV, float qscale) {
  const int z = blockIdx.z;
  if (z < 3) {
    const float* in = (z == 0) ? wq_w : (z == 1) ? wk_w : wv_w;
    transpose_tile(in, WT + (size_t)z * 1024 * 1024, 1024, 1024,
                   (z == 0) ? qscale : 1.0f, blockIdx.x * 32, blockIdx.y * 32);
    return;
  }
  // z == 3: cast + concat
  const int fb = blockIdx.y * 32 + blockIdx.x;         // 0..1023
  const int t = threadIdx.y * 32 + threadIdx.x;        // 0..255
  const size_t base = (size_t)fb * 4096;
  for (int j = 0; j < 4; j++) {
    size_t i0 = base + (size_t)j * 1024 + t * 4;
    float4 f = *reinterpret_cast<const float4*>(x + i0);
    short* o = (short*)Xbf + i0;
    o[0] = f2b(f.x); o[1] = f2b(f.y); o[2] = f2b(f.z); o[3] = f2b(f.w);
  }
  if (fb == 0) {
    for (int i = t; i < 3072; i += 256) {
      float v;
      if (i < 1024)       v = wq_b[i] * qscale;
      else if (i < 2048)  v = wk_b[i - 1024];
      else                v = wv_b[i - 2048];
      BQKV[i] = v;
    }
  }
}

// ---------------------------------------------------------------------------
// Fused phase-4 prep: transpose wo (z=0) + PROJ bias fill (z=1).
// grid (32,32,2), block (32,8).
// ---------------------------------------------------------------------------
__global__ __launch_bounds__(256) void prep_wo(
    const float* __restrict__ wo_w, bf16* __restrict__ WT,
    const float* __restrict__ wo_b, float* __restrict__ PROJ) {
  if (blockIdx.z == 0) {
    transpose_tile(wo_w, WT, 1024, 1024, 1.0f, blockIdx.x * 32, blockIdx.y * 32);
    return;
  }
  const int fb = blockIdx.y * 32 + blockIdx.x;         // 0..1023
  const int t = threadIdx.y * 32 + threadIdx.x;        // 0..255
  float4 bv = *reinterpret_cast<const float4*>(wo_b + t * 4);
  for (int j = 0; j < 4; j++)
    *reinterpret_cast<float4*>(PROJ + (size_t)(fb * 4 + j) * 1024 + t * 4) = bv;
}

// ---------------------------------------------------------------------------
// Fused phase-7 prep: transpose f2w (by<128) + out bias fill (by>=128).
// grid (32,160), block (32,8).
// ---------------------------------------------------------------------------
__global__ __launch_bounds__(256) void prep_ff2(
    const float* __restrict__ f2w, bf16* __restrict__ WT,
    const float* __restrict__ f2b_, float* __restrict__ out) {
  if (blockIdx.y < 128) {
    transpose_tile(f2w, WT, 4096, 1024, 1.0f, blockIdx.x * 32, blockIdx.y * 32);
    return;
  }
  const int fb = (blockIdx.y - 128) * 32 + blockIdx.x; // 0..1023
  const int t = threadIdx.y * 32 + threadIdx.x;        // 0..255
  float4 bv = *reinterpret_cast<const float4*>(f2b_ + t * 4);
  for (int j = 0; j < 4; j++)
    *reinterpret_cast<float4*>(out + (size_t)(fb * 4 + j) * 1024 + t * 4) = bv;
}

// ---------------------------------------------------------------------------
extern "C" void kernel_launch(void* const* d_in, const int* in_sizes, int n_in,
                              void* d_out, int out_size, void* d_ws, size_t ws_size,
                              hipStream_t stream) {
  (void)in_sizes; (void)n_in; (void)out_size; (void)ws_size;
  const float* x    = (const float*)d_in[0];
  const int*   mask = (const int*)d_in[1];
  const float* wq_w = (const float*)d_in[2];
  const float* wq_b = (const float*)d_in[3];
  const float* wk_w = (const float*)d_in[4];
  const float* wk_b = (const float*)d_in[5];
  const float* wv_w = (const float*)d_in[6];
  const float* wv_b = (const float*)d_in[7];
  const float* wo_w = (const float*)d_in[8];
  const float* wo_b = (const float*)d_in[9];
  const float* g1   = (const float*)d_in[10];
  const float* be1  = (const float*)d_in[11];
  const float* f1w  = (const float*)d_in[12];
  const float* f1b  = (const float*)d_in[13];
  const float* f2w  = (const float*)d_in[14];
  const float* f2b_ = (const float*)d_in[15];
  const float* g2   = (const float*)d_in[16];
  const float* be2  = (const float*)d_in[17];
  float* out = (float*)d_out;
  char* ws = (char*)d_ws;

  // ws layout (peak 48 MiB, time-shared):
  //  [0,24M)   QKV (ph2-3) -> PROJ fp32 [0,16M) (ph4-5) -> H [0,32M) (ph6-7)
  //  [24M,32M) Xbf (ph1-2) -> AO (ph3-4)
  //  [32M,40M) X1  (ph5-8)
  //  [40M,48M) WT  (transposed weights, per-phase)  + BQKV fp32 tail
  bf16*  QKV  = (bf16*)(ws + 0);
  bf16*  Xbf  = (bf16*)(ws + 25165824);
  bf16*  AO   = (bf16*)(ws + 25165824);
  float* PROJ = (float*)(ws + 0);
  bf16*  H    = (bf16*)(ws + 0);
  bf16*  X1   = (bf16*)(ws + 33554432);
  bf16*  WT   = (bf16*)(ws + 41943040);
  float* BQKV = (float*)(ws + 48234496);

  const float QSCALE = 0.18033688f;  // (1/sqrt(64)) * log2(e)

  dim3 tb(32, 8);
  // phase 1: fused prep (3 weight transposes + x cast + bias concat)
  prep_qkv<<<dim3(32, 32, 4), tb, 0, stream>>>(
      wq_w, wk_w, wv_w, WT, x, Xbf, wq_b, wk_b, wv_b, BQKV, QSCALE);
  // phase 2: fused QKV projection — 128² BK=64 pipeline, 768 blocks
  gemm_bt128<<<dim3(24, 32), dim3(256), 0, stream>>>(Xbf, WT, BQKV, QKV, 1024, 3072, 0, 0);
  // phase 3: attention (512 blocks: 16 q-blocks x 32 bh, KVBLK=64)
  attn_kernel<<<dim3(16, 32), dim3(256), 0, stream>>>(QKV, mask, AO);
  // phase 4: fused prep (wo transpose + PROJ bias fill; must follow attn —
  // PROJ aliases QKV), then WO projection — BK=64 pipeline, split-K=2
  prep_wo<<<dim3(32, 32, 2), tb, 0, stream>>>(wo_w, WT, wo_b, PROJ);
  gemm_pipe<<<dim3(8, 32, 2), dim3(256), 0, stream>>>(AO, WT, PROJ, 1024, 1024, 512);
  // phase 5: LN1 (a = PROJ fp32, xres = original fp32 x)
  ln_resid<<<dim3(4096), dim3(256), 0, stream>>>(PROJ, x, g1, be1, X1, 1, 1, 0);
  // phase 6: FFN up — 128² BK=64 pipeline, 1024 blocks
  transpose_k<<<dim3(128, 32), tb, 0, stream>>>(f1w, WT, 1024, 4096, 1.0f);
  gemm_bt128<<<dim3(32, 32), dim3(256), 0, stream>>>(X1, WT, f1b, H, 1024, 4096, 1, 0);
  // phase 7: fused prep (f2w transpose + out bias fill; must follow FF1 —
  // overwrites WT), then FFN down — BK=64 pipeline, split-K=2
  prep_ff2<<<dim3(32, 160), tb, 0, stream>>>(f2w, WT, f2b_, out);
  gemm_pipe<<<dim3(8, 32, 2), dim3(256), 0, stream>>>(H, WT, out, 4096, 1024, 2048);
  // phase 8: LN2 in-place on d_out (fp32 a, bf16 xres, fp32 out)
  ln_resid<<<dim3(4096), dim3(256), 0, stream>>>(out, X1, g2, be2, out, 1, 0, 1);
}

// Round 20
// 400.497 us; speedup vs baseline: 1.0795x; 1.0127x over previous
//
#include <hip/hip_runtime.h>
#include <hip/hip_bf16.h>
#include <cstdint>
#include <cstddef>

using bf16 = __hip_bfloat16;
typedef __attribute__((ext_vector_type(8))) short short8v;   // MFMA A/B frag: 8 bf16
typedef __attribute__((ext_vector_type(4))) short short4v;   // 4 bf16 (b64 load/store)
typedef __attribute__((ext_vector_type(4))) float float4v;   // MFMA C/D frag

__device__ inline float b2f(short s) {
  union { float f; uint32_t u; } z; z.u = ((uint32_t)(uint16_t)s) << 16; return z.f;
}
__device__ inline short f2b(float f) {
  bf16 h = __float2bfloat16(f);
  return *reinterpret_cast<short*>(&h);
}

typedef const __attribute__((address_space(1))) uint32_t* gas1p;
typedef __attribute__((address_space(3))) uint32_t* las3p;
__device__ inline void gload_lds16(const void* g, void* l) {
  __builtin_amdgcn_global_load_lds((gas1p)g, (las3p)l, 16, 0, 0);
}

// T1 XCD swizzle. Round-11 PMC confirmed: co-locates panel-sharing blocks on
// one XCD's L2 (gemm_pipe FETCH dropped 135 MB -> 32.8 MB compulsory).
__device__ inline void xcd_swizzle(int& bx, int& by, int& bz) {
  const int gx = gridDim.x, gy = gridDim.y;
  const int nwg = gx * gy * gridDim.z;
  const int wgid = blockIdx.x + gx * (blockIdx.y + gy * blockIdx.z);
  const int swz = (wgid & 7) * (nwg >> 3) + (wgid >> 3);
  bx = swz % gx;
  by = (swz / gx) % gy;
  bz = swz / (gx * gy);
}

// ---------------------------------------------------------------------------
// 128²-tile GEMM for QKV/FF1: BK=64 as two BK=32 halves, double-buffered LDS,
// ONE barrier/iter, XCD swizzle; bias/ReLU/bf16 epilogue. LDS 64 KB ->
// 2 blocks/CU resident.
// ---------------------------------------------------------------------------
__global__ __launch_bounds__(256) void gemm_bt128(
    const bf16* __restrict__ A, const bf16* __restrict__ Bt,
    const float* __restrict__ bias, void* __restrict__ C,
    int K, int ldc, int relu_mode, int out_f32) {
  __shared__ __align__(16) bf16 As[2][2][128 * 32];  // [buf][half][tile]
  __shared__ __align__(16) bf16 Bs[2][2][128 * 32];
  const int tid = threadIdx.x;
  const int w = tid >> 6, lane = tid & 63;
  const int quad = lane >> 4, l16 = lane & 15;
  const int wrow = (w >> 1) * 64, wcol = (w & 1) * 64;
  int bx, by, bz;
  xcd_swizzle(bx, by, bz);
  const int mbase = by * 128, nbase = bx * 128;
  const int c0 = w * 128 + lane;           // chunk ids c0 and c0+64
  const int row0 = c0 >> 2, p0 = c0 & 3;
  const int row1 = (c0 + 64) >> 2, p1 = (c0 + 64) & 3;

  const bf16* ag0 = A + (size_t)(mbase + row0) * K + p0 * 8;
  const bf16* ag1 = A + (size_t)(mbase + row1) * K + p1 * 8;
  const bf16* bg0 = Bt + (size_t)(nbase + row0) * K + p0 * 8;
  const bf16* bg1 = Bt + (size_t)(nbase + row1) * K + p1 * 8;

  // stage 64-col tile t64 into buffer bi (two BK=32 halves)
  auto stage = [&](int t64, int bi) {
    const int ko = t64 * 64;
#pragma unroll
    for (int h = 0; h < 2; h++) {
      char* da = (char*)As + (size_t)(bi * 2 + h) * 8192 + w * 2048;
      char* db = (char*)Bs + (size_t)(bi * 2 + h) * 8192 + w * 2048;
      gload_lds16(ag0 + ko + h * 32, da);
      gload_lds16(ag1 + ko + h * 32, da + 1024);
      gload_lds16(bg0 + ko + h * 32, db);
      gload_lds16(bg1 + ko + h * 32, db + 1024);
    }
  };

  float4v acc[4][4];
  for (int i = 0; i < 4; i++)
    for (int j = 0; j < 4; j++) acc[i][j] = (float4v){0.f, 0.f, 0.f, 0.f};

  const int KT2 = K >> 6;
  // prologue: tile 0 -> buf 0
  stage(0, 0);
  __syncthreads();

  for (int kt = 0; kt < KT2; kt++) {
    const int pb = kt & 1;
    if (kt + 1 < KT2) stage(kt + 1, 1 - pb);  // issued early, drained at barrier

#pragma unroll
    for (int h = 0; h < 2; h++) {
      const bf16* Ah = &As[pb][h][0];
      const bf16* Bh = &Bs[pb][h][0];
      short8v a[4], b[4];
      for (int mt = 0; mt < 4; mt++)
        a[mt] = *reinterpret_cast<const short8v*>(Ah + (wrow + mt * 16 + l16) * 32 + quad * 8);
      for (int nt = 0; nt < 4; nt++)
        b[nt] = *reinterpret_cast<const short8v*>(Bh + (wcol + nt * 16 + l16) * 32 + quad * 8);
      for (int mt = 0; mt < 4; mt++)
        for (int nt = 0; nt < 4; nt++)
          acc[mt][nt] = __builtin_amdgcn_mfma_f32_16x16x32_bf16(a[mt], b[nt], acc[mt][nt], 0, 0, 0);
    }

    __syncthreads();  // drains vmcnt (next tile valid) + lgkm (reads done)
  }

  // epilogue: D row = quad*4+reg, col = lane&15
  for (int nt = 0; nt < 4; nt++) {
    int col = nbase + wcol + nt * 16 + l16;
    float bv = bias[col];
    for (int mt = 0; mt < 4; mt++) {
      int row = mbase + wrow + mt * 16 + quad * 4;
      for (int r = 0; r < 4; r++) {
        float v = acc[mt][nt][r] + bv;
        if (relu_mode) v = fmaxf(v, 0.f);
        size_t idx = (size_t)(row + r) * ldc + col;
        if (out_f32) ((float*)C)[idx] = v;
        else         ((short*)C)[idx] = f2b(v);
      }
    }
  }
}

// ---------------------------------------------------------------------------
// Pipelined split-K GEMM for WO/FF2. v4: BK=64 per barrier as two BK=32
// halves, double-buffered, one barrier/iter, + T1 XCD swizzle. Split-K FIXED
// at 2 (round-15: split-K=4 regressed via atomic contention at the LDS-capped
// 2 blocks/CU). blockIdx.z selects a K-slice; partial sums atomicAdd into
// fp32 C (bias pre-initialized).
// ---------------------------------------------------------------------------
__global__ __launch_bounds__(256) void gemm_pipe(
    const bf16* __restrict__ A, const bf16* __restrict__ Bt,
    float* __restrict__ C, int K, int ldc, int k_len) {
  __shared__ __align__(16) bf16 As[2][2][128 * 32];  // [buf][half][tile]
  __shared__ __align__(16) bf16 Bs[2][2][128 * 32];
  const int tid = threadIdx.x;
  const int w = tid >> 6, lane = tid & 63;
  const int quad = lane >> 4, l16 = lane & 15;
  const int wrow = (w >> 1) * 64, wcol = (w & 1) * 64;
  int bx, by, bz;
  xcd_swizzle(bx, by, bz);
  const int mbase = by * 128, nbase = bx * 128;
  const int c0 = w * 128 + lane;           // chunk ids c0 and c0+64
  const int row0 = c0 >> 2, p0 = c0 & 3;
  const int row1 = (c0 + 64) >> 2, p1 = (c0 + 64) & 3;
  const int kbase = bz * k_len;

  const bf16* ag0 = A + (size_t)(mbase + row0) * K + kbase + p0 * 8;
  const bf16* ag1 = A + (size_t)(mbase + row1) * K + kbase + p1 * 8;
  const bf16* bg0 = Bt + (size_t)(nbase + row0) * K + kbase + p0 * 8;
  const bf16* bg1 = Bt + (size_t)(nbase + row1) * K + kbase + p1 * 8;

  // stage 64-col tile t64 into buffer bi (two BK=32 halves)
  auto stage = [&](int t64, int bi) {
    const int ko = t64 * 64;
#pragma unroll
    for (int h = 0; h < 2; h++) {
      char* da = (char*)As + (size_t)(bi * 2 + h) * 8192 + w * 2048;
      char* db = (char*)Bs + (size_t)(bi * 2 + h) * 8192 + w * 2048;
      gload_lds16(ag0 + ko + h * 32, da);
      gload_lds16(ag1 + ko + h * 32, da + 1024);
      gload_lds16(bg0 + ko + h * 32, db);
      gload_lds16(bg1 + ko + h * 32, db + 1024);
    }
  };

  float4v acc[4][4];
  for (int i = 0; i < 4; i++)
    for (int j = 0; j < 4; j++) acc[i][j] = (float4v){0.f, 0.f, 0.f, 0.f};

  const int KT2 = k_len >> 6;
  // prologue: tile 0 -> buf 0
  stage(0, 0);
  __syncthreads();

  for (int kt = 0; kt < KT2; kt++) {
    const int pb = kt & 1;
    if (kt + 1 < KT2) stage(kt + 1, 1 - pb);  // issued early, drained at barrier

#pragma unroll
    for (int h = 0; h < 2; h++) {
      const bf16* Ah = &As[pb][h][0];
      const bf16* Bh = &Bs[pb][h][0];
      short8v a[4], b[4];
      for (int mt = 0; mt < 4; mt++)
        a[mt] = *reinterpret_cast<const short8v*>(Ah + (wrow + mt * 16 + l16) * 32 + quad * 8);
      for (int nt = 0; nt < 4; nt++)
        b[nt] = *reinterpret_cast<const short8v*>(Bh + (wcol + nt * 16 + l16) * 32 + quad * 8);
      for (int mt = 0; mt < 4; mt++)
        for (int nt = 0; nt < 4; nt++)
          acc[mt][nt] = __builtin_amdgcn_mfma_f32_16x16x32_bf16(a[mt], b[nt], acc[mt][nt], 0, 0, 0);
    }

    __syncthreads();  // drains vmcnt (next tile valid) + lgkm (reads done)
  }

  // epilogue: partial-sum atomicAdd (C pre-initialized with bias)
  for (int nt = 0; nt < 4; nt++) {
    int col = nbase + wcol + nt * 16 + l16;
    for (int mt = 0; mt < 4; mt++) {
      int row = mbase + wrow + mt * 16 + quad * 4;
      for (int r = 0; r < 4; r++)
        atomicAdd(&C[(size_t)(row + r) * ldc + col], acc[mt][nt][r]);
    }
  }
}

// ---------------------------------------------------------------------------
// Flash attention v10 (round-16 anchor config): 32 q/wave, 512 blocks,
// KVBLK=64 (two 32-kv subtiles per barrier) — 32 iterations. KVBLK=64 is the
// measured interior optimum (32: +15 µs, 128: +13 µs).
// ---------------------------------------------------------------------------
__global__ __launch_bounds__(256) void attn_kernel(
    const bf16* __restrict__ qkv, const int* __restrict__ mask,
    bf16* __restrict__ ao) {
  __shared__ __align__(16) short Vt[2][64 * 72];   // [buf][d][kv0..63], pitch 72
  __shared__ __align__(16) short Ks[2][64 * 64];   // [buf][kv][d], row-XOR-swizzled

  const int tid = threadIdx.x;
  const int w = tid >> 6, lane = tid & 63;
  const int quad = lane >> 4, l16 = lane & 15;
  const int bh = blockIdx.y, b = bh >> 4;
  const int row0 = bh * 128;                 // row base in qkv [4096,3072]
  const int qbase = blockIdx.x * 128 + w * 32;  // wave's 32 q rows
  const int kvp = tid & 15, dg = tid >> 4;   // V stager: kv rows 2kvp,2kvp+1; d 4dg..+3
  const int krow = tid >> 3, kc = tid & 7;   // K stager: rows krow & krow+32, chunk kc

  // Q fragments (B-operand of swapped QK^T); Q is pre-scaled by log2(e)/8
  short8v aq[2][2];
  for (int h = 0; h < 2; h++)
    for (int dh = 0; dh < 2; dh++) {
      int local = (qbase + h * 16 + l16) * 64 + dh * 32 + quad * 8;
      aq[h][dh] = *reinterpret_cast<const short8v*>(
          qkv + (size_t)(row0 + (local >> 10)) * 3072 + (local & 1023));
    }

  // K stage pointers (2 b128/thread cover the 64x64 tile)
  const bf16* pks0;
  {
    int local = krow * 64 + kc * 8;
    pks0 = qkv + (size_t)(row0 + (local >> 10)) * 3072 + (local & 1023) + 1024;
  }
  const bf16* pks1 = pks0 + 6144;
  // V stage pointers (2 kv rows x 4 d per thread, x2 subtiles)
  const bf16* pva;
  const bf16* pvb;
  {
    int la = (2 * kvp) * 64 + dg * 4;
    pva = qkv + (size_t)(row0 + (la >> 10)) * 3072 + (la & 1023) + 2048;
    int lb = (2 * kvp + 1) * 64 + dg * 4;
    pvb = qkv + (size_t)(row0 + (lb >> 10)) * 3072 + (lb & 1023) + 2048;
  }
  const bf16* pva2 = pva + 6144;
  const bf16* pvb2 = pvb + 6144;
  const int* pm = mask + b * 2048 + quad * 4;

  float4v o[2][4];
  for (int h = 0; h < 2; h++)
    for (int nt = 0; nt < 4; nt++) o[h][nt] = (float4v){0.f, 0.f, 0.f, 0.f};
  float4v lacc[2];
  lacc[0] = (float4v){0.f, 0.f, 0.f, 0.f};
  lacc[1] = (float4v){0.f, 0.f, 0.f, 0.f};
  short8v vone;
  for (int j = 0; j < 8; j++) vone[j] = (short)0x3F80;  // bf16 1.0 x8

  // prologue: load + stage tile 0 (64 kv rows)
  short8v kr0, kr1;
  short4v va, vb, va2, vb2;
  kr0 = *reinterpret_cast<const short8v*>(pks0);
  kr1 = *reinterpret_cast<const short8v*>(pks1);
  va  = *reinterpret_cast<const short4v*>(pva);
  vb  = *reinterpret_cast<const short4v*>(pvb);
  va2 = *reinterpret_cast<const short4v*>(pva2);
  vb2 = *reinterpret_cast<const short4v*>(pvb2);
  int4 mc0 = *reinterpret_cast<const int4*>(pm);
  int4 mc1 = *reinterpret_cast<const int4*>(pm + 16);
  int4 mc2 = *reinterpret_cast<const int4*>(pm + 32);
  int4 mc3 = *reinterpret_cast<const int4*>(pm + 48);
  pks0 += 12288; pks1 += 12288; pva += 12288; pvb += 12288;
  pva2 += 12288; pvb2 += 12288; pm += 64;
  {
    const int sw = (kc ^ (krow & 7)) << 3;
    *reinterpret_cast<short8v*>(&Ks[0][krow * 64 + sw]) = kr0;
    *reinterpret_cast<short8v*>(&Ks[0][(krow + 32) * 64 + sw]) = kr1;
    uint32_t* vt = reinterpret_cast<uint32_t*>(&Vt[0][0]);
    for (int i = 0; i < 4; i++) {
      vt[(dg * 4 + i) * 36 + kvp] =
          ((uint32_t)(uint16_t)vb[i] << 16) | (uint16_t)(uint16_t)va[i];
      vt[(dg * 4 + i) * 36 + 16 + kvp] =
          ((uint32_t)(uint16_t)vb2[i] << 16) | (uint16_t)(uint16_t)va2[i];
    }
  }
  __syncthreads();

  for (int it = 0; it < 32; it++) {
    const int pb = it & 1;
    short8v knr0, knr1;
    short4v vna, vnb, vna2, vnb2;
    int4 mn0, mn1, mn2, mn3;
    if (it < 31) {
      knr0 = *reinterpret_cast<const short8v*>(pks0);
      knr1 = *reinterpret_cast<const short8v*>(pks1);
      vna  = *reinterpret_cast<const short4v*>(pva);
      vnb  = *reinterpret_cast<const short4v*>(pvb);
      vna2 = *reinterpret_cast<const short4v*>(pva2);
      vnb2 = *reinterpret_cast<const short4v*>(pvb2);
      mn0 = *reinterpret_cast<const int4*>(pm);
      mn1 = *reinterpret_cast<const int4*>(pm + 16);
      mn2 = *reinterpret_cast<const int4*>(pm + 32);
      mn3 = *reinterpret_cast<const int4*>(pm + 48);
      pks0 += 12288; pks1 += 12288; pva += 12288; pvb += 12288;
      pva2 += 12288; pvb2 += 12288; pm += 64;
    }

#pragma unroll
    for (int sub = 0; sub < 2; sub++) {
      // K fragments from LDS (swizzled read: chunk (dh*4+quad) ^ (l16&7))
      short8v kc_[2][2];
      for (int s = 0; s < 2; s++)
        for (int dh = 0; dh < 2; dh++) {
          int rr = sub * 32 + s * 16 + l16;
          kc_[s][dh] = *reinterpret_cast<const short8v*>(
              &Ks[pb][rr * 64 + (((dh * 4 + quad) ^ (l16 & 7)) << 3)]);
        }

      float4v st[2][2];
      for (int s = 0; s < 2; s++)
        for (int h = 0; h < 2; h++) {
          float4v t = (float4v){0.f, 0.f, 0.f, 0.f};
          t = __builtin_amdgcn_mfma_f32_16x16x32_bf16(kc_[s][0], aq[h][0], t, 0, 0, 0);
          t = __builtin_amdgcn_mfma_f32_16x16x32_bf16(kc_[s][1], aq[h][1], t, 0, 0, 0);
          st[s][h] = t;
        }

      // softmax numerator + in-register P-fragment assembly (no LDS)
      short8v pf[2];
      for (int h = 0; h < 2; h++) {
        float ev[2][4];
        for (int s = 0; s < 2; s++) {
          int4 mv = sub ? (s ? mc3 : mc2) : (s ? mc1 : mc0);
          int mm[4] = {mv.x, mv.y, mv.z, mv.w};
          for (int r = 0; r < 4; r++) {
            float y = st[s][h][r];                    // already exp2-arg units
            y = (mm[r] == 0) ? -1.4427e-12f : y;      // faithful mask semantics
            ev[s][r] = __builtin_amdgcn_exp2f(y);
          }
        }
        uint32_t a0, a1, b0, b1;
        asm("v_cvt_pk_bf16_f32 %0, %1, %2" : "=v"(a0) : "v"(ev[0][0]), "v"(ev[0][1]));
        asm("v_cvt_pk_bf16_f32 %0, %1, %2" : "=v"(a1) : "v"(ev[0][2]), "v"(ev[0][3]));
        asm("v_cvt_pk_bf16_f32 %0, %1, %2" : "=v"(b0) : "v"(ev[1][0]), "v"(ev[1][1]));
        asm("v_cvt_pk_bf16_f32 %0, %1, %2" : "=v"(b1) : "v"(ev[1][2]), "v"(ev[1][3]));
        // halves: lanes<32 hold A-family (s=0), >=32 B-family (s=1)
        asm("v_permlane32_swap_b32 %0, %1" : "+v"(b0), "+v"(a0));
        asm("v_permlane16_swap_b32 %0, %1" : "+v"(b0), "+v"(a0));
        asm("v_permlane32_swap_b32 %0, %1" : "+v"(b1), "+v"(a1));
        asm("v_permlane16_swap_b32 %0, %1" : "+v"(b1), "+v"(a1));
        union { short8v s8; uint32_t u[4]; } pfu;
        pfu.u[0] = a0; pfu.u[1] = a1; pfu.u[2] = b0; pfu.u[3] = b1;
        pf[h] = pfu.s8;
      }

      for (int h = 0; h < 2; h++)
        lacc[h] = __builtin_amdgcn_mfma_f32_16x16x32_bf16(pf[h], vone, lacc[h], 0, 0, 0);
      for (int nt = 0; nt < 4; nt++) {
        short8v bv = *reinterpret_cast<const short8v*>(
            &Vt[pb][(nt * 16 + l16) * 72 + sub * 32 + quad * 8]);
        for (int h = 0; h < 2; h++)
          o[h][nt] = __builtin_amdgcn_mfma_f32_16x16x32_bf16(pf[h], bv, o[h][nt], 0, 0, 0);
      }
    }

    if (it < 31) {
      const int sw = (kc ^ (krow & 7)) << 3;
      *reinterpret_cast<short8v*>(&Ks[1 - pb][krow * 64 + sw]) = knr0;
      *reinterpret_cast<short8v*>(&Ks[1 - pb][(krow + 32) * 64 + sw]) = knr1;
      uint32_t* vt = reinterpret_cast<uint32_t*>(&Vt[1 - pb][0]);
      for (int i = 0; i < 4; i++) {
        vt[(dg * 4 + i) * 36 + kvp] =
            ((uint32_t)(uint16_t)vnb[i] << 16) | (uint16_t)(uint16_t)vna[i];
        vt[(dg * 4 + i) * 36 + 16 + kvp] =
            ((uint32_t)(uint16_t)vnb2[i] << 16) | (uint16_t)(uint16_t)vna2[i];
      }
      mc0 = mn0; mc1 = mn1; mc2 = mn2; mc3 = mn3;
    }
    __syncthreads();
  }

  // lacc[h][r] = rowsum(P) for q row quad*4+r (all 16 cols identical)
  for (int h = 0; h < 2; h++)
    for (int r = 0; r < 4; r++) {
      float linv = 1.0f / lacc[h][r];
      int qg = qbase + h * 16 + quad * 4 + r;
      for (int nt = 0; nt < 4; nt++) {
        int d = nt * 16 + l16;
        ao[(size_t)bh * 131072 + (size_t)qg * 64 + d] = __float2bfloat16(o[h][nt][r] * linv);
      }
    }
}

// ---------------------------------------------------------------------------
// LN body: out = LN(a + xres); unbiased std (ddof=1), /(std + 1e-12).
// One 256-thread block per row.
// ---------------------------------------------------------------------------
__device__ inline void ln_row(
    const void* __restrict__ a, const void* __restrict__ xres,
    const float* __restrict__ gamma, const float* __restrict__ beta,
    void* __restrict__ out, int a_f32, int x_f32, int out_f32,
    int row, int tid) {
  __shared__ float red[8];
  const int w = tid >> 6, lane = tid & 63;
  const size_t base = (size_t)row * 1024;
  float v[4]; float sum = 0.f, ss = 0.f;
  for (int i = 0; i < 4; i++) {
    int c = tid + i * 256;
    float av = a_f32 ? ((const float*)a)[base + c] : b2f(((const short*)a)[base + c]);
    float xv = x_f32 ? ((const float*)xres)[base + c] : b2f(((const short*)xres)[base + c]);
    v[i] = av + xv;
    sum += v[i]; ss += v[i] * v[i];
  }
  for (int off = 1; off < 64; off <<= 1) {
    sum += __shfl_xor(sum, off);
    ss  += __shfl_xor(ss, off);
  }
  if (lane == 0) { red[w * 2] = sum; red[w * 2 + 1] = ss; }
  __syncthreads();
  sum = red[0] + red[2] + red[4] + red[6];
  ss  = red[1] + red[3] + red[5] + red[7];
  float mean = sum * (1.0f / 1024.0f);
  float var = (ss - 1024.0f * mean * mean) * (1.0f / 1023.0f);
  var = fmaxf(var, 0.f);
  float rden = 1.0f / (sqrtf(var) + 1e-12f);
  for (int i = 0; i < 4; i++) {
    int c = tid + i * 256;
    float y = gamma[c] * ((v[i] - mean) * rden) + beta[c];
    if (out_f32) ((float*)out)[base + c] = y;
    else         ((short*)out)[base + c] = f2b(y);
  }
}

__global__ __launch_bounds__(256) void ln_resid(
    const void* __restrict__ a, const void* __restrict__ xres,
    const float* __restrict__ gamma, const float* __restrict__ beta,
    void* __restrict__ out, int a_f32, int x_f32, int out_f32) {
  ln_row(a, xres, gamma, beta, out, a_f32, x_f32, out_f32, blockIdx.x, threadIdx.x);
}

// ---------------------------------------------------------------------------
// Transpose body (explicit tx/ty so flat-256 fused blocks can call it):
// out(bf16)[c*R + r] = in(f32)[r*C + c] * scale, 32x32 tile at (cb, rb).
// ---------------------------------------------------------------------------
__device__ inline void transpose_tile(
    const float* __restrict__ in, bf16* __restrict__ out, int R, int C,
    float scale, int cb, int rb, int tx, int ty) {
  __shared__ short t[32][33];
  for (int j = 0; j < 4; j++)
    t[ty + j * 8][tx] = f2b(in[(size_t)(rb + ty + j * 8) * C + cb + tx] * scale);
  __syncthreads();
  for (int j = 0; j < 4; j++)
    ((short*)out)[(size_t)(cb + ty + j * 8) * R + rb + tx] = t[tx][ty + j * 8];
}

// ---------------------------------------------------------------------------
// Fused phase-5/6a (round 20): LN1 (blocks 0..4095) + f1w transpose
// (blocks 4096..8191) — independent memory-bound work, one dispatch,
// overlapped traffic. Both only legal after the WO gemm, preserved by the
// launch point. Flat 256-thread blocks.
// ---------------------------------------------------------------------------
__global__ __launch_bounds__(256) void ln1_prep_ff1(
    const float* __restrict__ PROJ, const float* __restrict__ x,
    const float* __restrict__ g1, const float* __restrict__ be1,
    bf16* __restrict__ X1,
    const float* __restrict__ f1w, bf16* __restrict__ WT) {
  if (blockIdx.x < 4096) {
    ln_row(PROJ, x, g1, be1, X1, 1, 1, 0, blockIdx.x, threadIdx.x);
    return;
  }
  const int idx = blockIdx.x - 4096;       // 0..4095
  const int bx = idx & 127, by = idx >> 7; // f1w grid was (128, 32)
  transpose_tile(f1w, WT, 1024, 4096, 1.0f, bx * 32, by * 32,
                 threadIdx.x & 31, threadIdx.x >> 5);
}

// ---------------------------------------------------------------------------
// Fused phase-1 prep. grid (32,32,4), block (32,8):
//  z=0..2: transpose wq/wk/wv -> WT+z*1M (wq scaled by QSCALE)
//  z=3:    cast x f32->bf16 (1024 flat blocks x 4096 elems) + concat3 (blk 0)
// ---------------------------------------------------------------------------
__global__ __launch_bounds__(256) void prep_qkv(
    const float* __restrict__ wq_w, const float* __restrict__ wk_w,
    const float* __restrict__ wv_w, bf16* __restrict__ WT,
    const float* __restrict__ x, bf16* __restrict__ Xbf,
    const float* __restrict__ wq_b, const float* __restrict__ wk_b,
    const float* __restrict__ wv_b, float* __restrict__ BQKV, float qscale) {
  const int z = blockIdx.z;
  if (z < 3) {
    const float* in = (z == 0) ? wq_w : (z == 1) ? wk_w : wv_w;
    transpose_tile(in, WT + (size_t)z * 1024 * 1024, 1024, 1024,
                   (z == 0) ? qscale : 1.0f, blockIdx.x * 32, blockIdx.y * 32,
                   threadIdx.x, threadIdx.y);
    return;
  }
  // z == 3: cast + concat
  const int fb = blockIdx.y * 32 + blockIdx.x;         // 0..1023
  const int t = threadIdx.y * 32 + threadIdx.x;        // 0..255
  const size_t base = (size_t)fb * 4096;
  for (int j = 0; j < 4; j++) {
    size_t i0 = base + (size_t)j * 1024 + t * 4;
    float4 f = *reinterpret_cast<const float4*>(x + i0);
    short* o = (short*)Xbf + i0;
    o[0] = f2b(f.x); o[1] = f2b(f.y); o[2] = f2b(f.z); o[3] = f2b(f.w);
  }
  if (fb == 0) {
    for (int i = t; i < 3072; i += 256) {
      float v;
      if (i < 1024)       v = wq_b[i] * qscale;
      else if (i < 2048)  v = wk_b[i - 1024];
      else                v = wv_b[i - 2048];
      BQKV[i] = v;
    }
  }
}

// ---------------------------------------------------------------------------
// Fused phase-4 prep: transpose wo (z=0) + PROJ bias fill (z=1).
// grid (32,32,2), block (32,8).
// ---------------------------------------------------------------------------
__global__ __launch_bounds__(256) void prep_wo(
    const float* __restrict__ wo_w, bf16* __restrict__ WT,
    const float* __restrict__ wo_b, float* __restrict__ PROJ) {
  if (blockIdx.z == 0) {
    transpose_tile(wo_w, WT, 1024, 1024, 1.0f, blockIdx.x * 32, blockIdx.y * 32,
                   threadIdx.x, threadIdx.y);
    return;
  }
  const int fb = blockIdx.y * 32 + blockIdx.x;         // 0..1023
  const int t = threadIdx.y * 32 + threadIdx.x;        // 0..255
  float4 bv = *reinterpret_cast<const float4*>(wo_b + t * 4);
  for (int j = 0; j < 4; j++)
    *reinterpret_cast<float4*>(PROJ + (size_t)(fb * 4 + j) * 1024 + t * 4) = bv;
}

// ---------------------------------------------------------------------------
// Fused phase-7 prep: transpose f2w (by<128) + out bias fill (by>=128).
// grid (32,160), block (32,8).
// ---------------------------------------------------------------------------
__global__ __launch_bounds__(256) void prep_ff2(
    const float* __restrict__ f2w, bf16* __restrict__ WT,
    const float* __restrict__ f2b_, float* __restrict__ out) {
  if (blockIdx.y < 128) {
    transpose_tile(f2w, WT, 4096, 1024, 1.0f, blockIdx.x * 32, blockIdx.y * 32,
                   threadIdx.x, threadIdx.y);
    return;
  }
  const int fb = (blockIdx.y - 128) * 32 + blockIdx.x; // 0..1023
  const int t = threadIdx.y * 32 + threadIdx.x;        // 0..255
  float4 bv = *reinterpret_cast<const float4*>(f2b_ + t * 4);
  for (int j = 0; j < 4; j++)
    *reinterpret_cast<float4*>(out + (size_t)(fb * 4 + j) * 1024 + t * 4) = bv;
}

// ---------------------------------------------------------------------------
extern "C" void kernel_launch(void* const* d_in, const int* in_sizes, int n_in,
                              void* d_out, int out_size, void* d_ws, size_t ws_size,
                              hipStream_t stream) {
  (void)in_sizes; (void)n_in; (void)out_size; (void)ws_size;
  const float* x    = (const float*)d_in[0];
  const int*   mask = (const int*)d_in[1];
  const float* wq_w = (const float*)d_in[2];
  const float* wq_b = (const float*)d_in[3];
  const float* wk_w = (const float*)d_in[4];
  const float* wk_b = (const float*)d_in[5];
  const float* wv_w = (const float*)d_in[6];
  const float* wv_b = (const float*)d_in[7];
  const float* wo_w = (const float*)d_in[8];
  const float* wo_b = (const float*)d_in[9];
  const float* g1   = (const float*)d_in[10];
  const float* be1  = (const float*)d_in[11];
  const float* f1w  = (const float*)d_in[12];
  const float* f1b  = (const float*)d_in[13];
  const float* f2w  = (const float*)d_in[14];
  const float* f2b_ = (const float*)d_in[15];
  const float* g2   = (const float*)d_in[16];
  const float* be2  = (const float*)d_in[17];
  float* out = (float*)d_out;
  char* ws = (char*)d_ws;

  // ws layout (peak 48 MiB, time-shared):
  //  [0,24M)   QKV (ph2-3) -> PROJ fp32 [0,16M) (ph4-5) -> H [0,32M) (ph6-7)
  //  [24M,32M) Xbf (ph1-2) -> AO (ph3-4)
  //  [32M,40M) X1  (ph5-8)
  //  [40M,48M) WT  (transposed weights, per-phase)  + BQKV fp32 tail
  bf16*  QKV  = (bf16*)(ws + 0);
  bf16*  Xbf  = (bf16*)(ws + 25165824);
  bf16*  AO   = (bf16*)(ws + 25165824);
  float* PROJ = (float*)(ws + 0);
  bf16*  H    = (bf16*)(ws + 0);
  bf16*  X1   = (bf16*)(ws + 33554432);
  bf16*  WT   = (bf16*)(ws + 41943040);
  float* BQKV = (float*)(ws + 48234496);

  const float QSCALE = 0.18033688f;  // (1/sqrt(64)) * log2(e)

  dim3 tb(32, 8);
  // phase 1: fused prep (3 weight transposes + x cast + bias concat)
  prep_qkv<<<dim3(32, 32, 4), tb, 0, stream>>>(
      wq_w, wk_w, wv_w, WT, x, Xbf, wq_b, wk_b, wv_b, BQKV, QSCALE);
  // phase 2: fused QKV projection — 128² BK=64 pipeline, 768 blocks
  gemm_bt128<<<dim3(24, 32), dim3(256), 0, stream>>>(Xbf, WT, BQKV, QKV, 1024, 3072, 0, 0);
  // phase 3: attention (512 blocks: 16 q-blocks x 32 bh, KVBLK=64)
  attn_kernel<<<dim3(16, 32), dim3(256), 0, stream>>>(QKV, mask, AO);
  // phase 4: fused prep (wo transpose + PROJ bias fill; must follow attn —
  // PROJ aliases QKV), then WO projection — BK=64 pipeline, split-K=2
  prep_wo<<<dim3(32, 32, 2), tb, 0, stream>>>(wo_w, WT, wo_b, PROJ);
  gemm_pipe<<<dim3(8, 32, 2), dim3(256), 0, stream>>>(AO, WT, PROJ, 1024, 1024, 512);
  // phase 5+6a: fused LN1 + f1w transpose (independent; both after WO gemm)
  ln1_prep_ff1<<<dim3(8192), dim3(256), 0, stream>>>(PROJ, x, g1, be1, X1, f1w, WT);
  // phase 6: FFN up — 128² BK=64 pipeline, 1024 blocks
  gemm_bt128<<<dim3(32, 32), dim3(256), 0, stream>>>(X1, WT, f1b, H, 1024, 4096, 1, 0);
  // phase 7: fused prep (f2w transpose + out bias fill; must follow FF1 —
  // overwrites WT), then FFN down — BK=64 pipeline, split-K=2
  prep_ff2<<<dim3(32, 160), tb, 0, stream>>>(f2w, WT, f2b_, out);
  gemm_pipe<<<dim3(8, 32, 2), dim3(256), 0, stream>>>(H, WT, out, 4096, 1024, 2048);
  // phase 8: LN2 in-place on d_out (fp32 a, bf16 xres, fp32 out)
  ln_resid<<<dim3(4096), dim3(256), 0, stream>>>(out, X1, g2, be2, out, 1, 0, 1);
}